// Round 4
// baseline (576.717 us; speedup 1.0000x reference)
//
#include <hip/hip_runtime.h>
#include <hip/hip_fp16.h>

#define BATCH_N   2048
#define EMB_D_    768
#define PROJ_D_   128
#define QUEUE_N   32768
#define HARD_K_   512
#define CAP_      8192
static constexpr float INV_T  = 1.0f / 0.07f;
static constexpr float PRETHR = 0.12f;   // candidate pre-threshold (512th opp value ~0.164)

typedef __attribute__((ext_vector_type(8))) short short8;
typedef __attribute__((ext_vector_type(4))) short short4v;
typedef __attribute__((ext_vector_type(4))) float f32x4;

__device__ __forceinline__ unsigned short f2bf(float f) {
    unsigned u = __float_as_uint(f);
    unsigned r = u + 0x7fffu + ((u >> 16) & 1u);   // RNE
    return (unsigned short)(r >> 16);
}
__device__ __forceinline__ float bf2f(short s) {
    return __uint_as_float(((unsigned)(unsigned short)s) << 16);
}
__device__ __forceinline__ int opp_of(int mylab, const int* __restrict__ qcnt) {
    const int same = (mylab == 0) ? qcnt[0] : ((mylab == 1) ? qcnt[1] : 0);
    return qcnt[2] - same;
}

// ---------------------------------------------------------------------------
// bf16 MFMA NT GEMM, K=128, unmasked fp32 store (for S). Verified r2/r3.
// ---------------------------------------------------------------------------
__global__ void __launch_bounds__(256) mfma_nt_plain(const short* __restrict__ Ab,
                                                     const short* __restrict__ Bb,
                                                     float* __restrict__ C, int N) {
    __shared__ __align__(16) short As[128 * 128];
    __shared__ __align__(16) short Bs[128 * 128];
    const int t = threadIdx.x;
    const int lane = t & 63, wv = t >> 6;
    const int l16 = lane & 15, l4 = lane >> 4;
    const int m0 = blockIdx.y * 128, n0 = blockIdx.x * 128;

    #pragma unroll
    for (int it = 0; it < 8; ++it) {
        const int r = it * 4 + wv, row = r * 4 + l4, cg = l16 ^ (row & 15);
        __builtin_amdgcn_global_load_lds(
            (const __attribute__((address_space(1))) void*)(Ab + (size_t)(m0 + row) * 128 + cg * 8),
            (__attribute__((address_space(3))) void*)(As + r * 512), 16, 0, 0);
    }
    #pragma unroll
    for (int it = 0; it < 8; ++it) {
        const int r = it * 4 + wv, row = r * 4 + l4, cg = l16 ^ (row & 15);
        __builtin_amdgcn_global_load_lds(
            (const __attribute__((address_space(1))) void*)(Bb + (size_t)(n0 + row) * 128 + cg * 8),
            (__attribute__((address_space(3))) void*)(Bs + r * 512), 16, 0, 0);
    }
    __syncthreads();

    const int wm = (wv & 1) * 64, wn = (wv >> 1) * 64;
    f32x4 acc[4][4];
    #pragma unroll
    for (int i = 0; i < 4; ++i)
        #pragma unroll
        for (int j = 0; j < 4; ++j) acc[i][j] = f32x4{0.f, 0.f, 0.f, 0.f};

    #pragma unroll
    for (int ks = 0; ks < 4; ++ks) {
        short8 af[4], bfr[4];
        const int ch = (ks * 4 + l4) ^ l16;
        #pragma unroll
        for (int i = 0; i < 4; ++i) {
            af[i]  = *(const short8*)(As + (wm + i * 16 + l16) * 128 + ch * 8);
            bfr[i] = *(const short8*)(Bs + (wn + i * 16 + l16) * 128 + ch * 8);
        }
        #pragma unroll
        for (int i = 0; i < 4; ++i)
            #pragma unroll
            for (int j = 0; j < 4; ++j)
                acc[i][j] = __builtin_amdgcn_mfma_f32_16x16x32_bf16(af[i], bfr[j], acc[i][j], 0, 0, 0);
    }
    #pragma unroll
    for (int i = 0; i < 4; ++i)
        #pragma unroll
        for (int r = 0; r < 4; ++r) {
            const int m = m0 + wm + i * 16 + l4 * 4 + r;
            #pragma unroll
            for (int j = 0; j < 4; ++j)
                C[(size_t)m * N + n0 + wn + j * 16 + l16] = acc[i][j][r];
        }
}

// ---------------------------------------------------------------------------
// Masked queue GEMM with fused candidate pruning. No sims materialization:
// opposite-label values >= PRETHR go to cand[row][slot] via padded atomics.
// ---------------------------------------------------------------------------
__global__ void __launch_bounds__(256) mfma_nt_prune(const short* __restrict__ Ab,
                                                     const short* __restrict__ Bb,
                                                     float* __restrict__ cand,
                                                     int* __restrict__ cnt,
                                                     const int* __restrict__ labA,
                                                     const int* __restrict__ labB) {
    __shared__ __align__(16) short As[128 * 128];
    __shared__ __align__(16) short Bs[128 * 128];
    const int t = threadIdx.x;
    const int lane = t & 63, wv = t >> 6;
    const int l16 = lane & 15, l4 = lane >> 4;
    const int m0 = blockIdx.y * 128, n0 = blockIdx.x * 128;

    #pragma unroll
    for (int it = 0; it < 8; ++it) {
        const int r = it * 4 + wv, row = r * 4 + l4, cg = l16 ^ (row & 15);
        __builtin_amdgcn_global_load_lds(
            (const __attribute__((address_space(1))) void*)(Ab + (size_t)(m0 + row) * 128 + cg * 8),
            (__attribute__((address_space(3))) void*)(As + r * 512), 16, 0, 0);
    }
    #pragma unroll
    for (int it = 0; it < 8; ++it) {
        const int r = it * 4 + wv, row = r * 4 + l4, cg = l16 ^ (row & 15);
        __builtin_amdgcn_global_load_lds(
            (const __attribute__((address_space(1))) void*)(Bb + (size_t)(n0 + row) * 128 + cg * 8),
            (__attribute__((address_space(3))) void*)(Bs + r * 512), 16, 0, 0);
    }
    __syncthreads();

    const int wm = (wv & 1) * 64, wn = (wv >> 1) * 64;
    f32x4 acc[4][4];
    #pragma unroll
    for (int i = 0; i < 4; ++i)
        #pragma unroll
        for (int j = 0; j < 4; ++j) acc[i][j] = f32x4{0.f, 0.f, 0.f, 0.f};

    #pragma unroll
    for (int ks = 0; ks < 4; ++ks) {
        short8 af[4], bfr[4];
        const int ch = (ks * 4 + l4) ^ l16;
        #pragma unroll
        for (int i = 0; i < 4; ++i) {
            af[i]  = *(const short8*)(As + (wm + i * 16 + l16) * 128 + ch * 8);
            bfr[i] = *(const short8*)(Bs + (wn + i * 16 + l16) * 128 + ch * 8);
        }
        #pragma unroll
        for (int i = 0; i < 4; ++i)
            #pragma unroll
            for (int j = 0; j < 4; ++j)
                acc[i][j] = __builtin_amdgcn_mfma_f32_16x16x32_bf16(af[i], bfr[j], acc[i][j], 0, 0, 0);
    }

    int qn[4];
    #pragma unroll
    for (int j = 0; j < 4; ++j) qn[j] = labB[n0 + wn + j * 16 + l16];
    #pragma unroll
    for (int i = 0; i < 4; ++i) {
        #pragma unroll
        for (int r = 0; r < 4; ++r) {
            const int m  = m0 + wm + i * 16 + l4 * 4 + r;
            const int lm = labA[m];
            #pragma unroll
            for (int j = 0; j < 4; ++j) {
                const float v = acc[i][j][r];
                if (qn[j] != lm && qn[j] >= 0 && v >= PRETHR) {
                    const int slot = atomicAdd(&cnt[m * 16], 1);
                    if (slot < CAP_) cand[(size_t)m * CAP_ + slot] = v;
                }
            }
        }
    }
}

// ---------------------------------------------------------------------------
// bf16 MFMA NT GEMM with K-loop, fused bias(+ReLU). Verified r3 (MLP).
// ---------------------------------------------------------------------------
template<typename OutT, bool RELU>
__global__ void __launch_bounds__(256) mfma_nt_k(const short* __restrict__ Ab,
                                                 const short* __restrict__ Bb,
                                                 const float* __restrict__ bias,
                                                 OutT* __restrict__ C,
                                                 int N, int K) {
    __shared__ __align__(16) short As[128 * 128];
    __shared__ __align__(16) short Bs[128 * 128];
    const int t = threadIdx.x;
    const int lane = t & 63, wv = t >> 6;
    const int l16 = lane & 15, l4 = lane >> 4;
    const int m0 = blockIdx.y * 128, n0 = blockIdx.x * 128;
    const int wm = (wv & 1) * 64, wn = (wv >> 1) * 64;

    f32x4 acc[4][4];
    #pragma unroll
    for (int i = 0; i < 4; ++i)
        #pragma unroll
        for (int j = 0; j < 4; ++j) acc[i][j] = f32x4{0.f, 0.f, 0.f, 0.f};

    for (int kb = 0; kb < K; kb += 128) {
        __syncthreads();
        #pragma unroll
        for (int it = 0; it < 8; ++it) {
            const int r = it * 4 + wv, row = r * 4 + l4, cg = l16 ^ (row & 15);
            __builtin_amdgcn_global_load_lds(
                (const __attribute__((address_space(1))) void*)(Ab + (size_t)(m0 + row) * K + kb + cg * 8),
                (__attribute__((address_space(3))) void*)(As + r * 512), 16, 0, 0);
        }
        #pragma unroll
        for (int it = 0; it < 8; ++it) {
            const int r = it * 4 + wv, row = r * 4 + l4, cg = l16 ^ (row & 15);
            __builtin_amdgcn_global_load_lds(
                (const __attribute__((address_space(1))) void*)(Bb + (size_t)(n0 + row) * K + kb + cg * 8),
                (__attribute__((address_space(3))) void*)(Bs + r * 512), 16, 0, 0);
        }
        __syncthreads();
        #pragma unroll
        for (int ks = 0; ks < 4; ++ks) {
            short8 af[4], bfr[4];
            const int ch = (ks * 4 + l4) ^ l16;
            #pragma unroll
            for (int i = 0; i < 4; ++i) {
                af[i]  = *(const short8*)(As + (wm + i * 16 + l16) * 128 + ch * 8);
                bfr[i] = *(const short8*)(Bs + (wn + i * 16 + l16) * 128 + ch * 8);
            }
            #pragma unroll
            for (int i = 0; i < 4; ++i)
                #pragma unroll
                for (int j = 0; j < 4; ++j)
                    acc[i][j] = __builtin_amdgcn_mfma_f32_16x16x32_bf16(af[i], bfr[j], acc[i][j], 0, 0, 0);
        }
    }

    float bsv[4];
    #pragma unroll
    for (int j = 0; j < 4; ++j) bsv[j] = bias[n0 + wn + j * 16 + l16];
    #pragma unroll
    for (int i = 0; i < 4; ++i)
        #pragma unroll
        for (int r = 0; r < 4; ++r) {
            const int m = m0 + wm + i * 16 + l4 * 4 + r;
            #pragma unroll
            for (int j = 0; j < 4; ++j) {
                const int n = n0 + wn + j * 16 + l16;
                float v = acc[i][j][r] + bsv[j];
                if (RELU) v = fmaxf(v, 0.0f);
                if constexpr (sizeof(OutT) == 2) ((short*)C)[(size_t)m * N + n] = (short)f2bf(v);
                else                             ((float*)C)[(size_t)m * N + n] = v;
            }
        }
}

// ---------------------------------------------------------------------------
__global__ void __launch_bounds__(256) transpose_cast(const float* __restrict__ A,
                                                      short* __restrict__ At,
                                                      int R, int C) {
    __shared__ float tile[64][65];
    const int bx = blockIdx.x * 64, by = blockIdx.y * 64;
    const int t = threadIdx.x, tc = t & 63, tg = t >> 6;
    #pragma unroll
    for (int i = 0; i < 16; i++) {
        const int r = tg * 16 + i;
        tile[r][tc] = A[(size_t)(by + r) * C + bx + tc];
    }
    __syncthreads();
    #pragma unroll
    for (int i = 0; i < 16; i++) {
        const int r = tg * 16 + i;
        At[(size_t)(bx + r) * R + by + tc] = (short)f2bf(tile[tc][r]);
    }
}

__global__ void normalize_cast(const float* __restrict__ z, short* __restrict__ zb) {
    const int row = blockIdx.x, t = threadIdx.x;
    const float v = z[(size_t)row * PROJ_D_ + t];
    float ss = v * v;
    #pragma unroll
    for (int o = 32; o > 0; o >>= 1) ss += __shfl_down(ss, o);
    __shared__ float s2[2];
    if ((t & 63) == 0) s2[t >> 6] = ss;
    __syncthreads();
    zb[(size_t)row * PROJ_D_ + t] = (short)f2bf(v / sqrtf(s2[0] + s2[1]));
}

__global__ void cast_bf16_vec(const float* __restrict__ src, short* __restrict__ dst, int n4) {
    const int i = blockIdx.x * blockDim.x + threadIdx.x;
    if (i < n4) {
        const float4 f = ((const float4*)src)[i];
        short4v o = {(short)f2bf(f.x), (short)f2bf(f.y), (short)f2bf(f.z), (short)f2bf(f.w)};
        ((short4v*)dst)[i] = o;
    }
}

// queue-label census: qcnt[0]=#{==0}, qcnt[1]=#{==1}, qcnt[2]=#{>=0}
__global__ void count_qlab(const int* __restrict__ qlab, int* __restrict__ qcnt) {
    const int i = blockIdx.x * 256 + threadIdx.x;
    int c0 = 0, c1 = 0, cv = 0;
    for (int j = i; j < QUEUE_N; j += 8192) {
        const int q = qlab[j];
        c0 += (q == 0); c1 += (q == 1); cv += (q >= 0);
    }
    #pragma unroll
    for (int o = 32; o > 0; o >>= 1) {
        c0 += __shfl_xor(c0, o); c1 += __shfl_xor(c1, o); cv += __shfl_xor(cv, o);
    }
    if ((threadIdx.x & 63) == 0) {
        atomicAdd(&qcnt[0], c0); atomicAdd(&qcnt[1], c1); atomicAdd(&qcnt[2], cv);
    }
}

// ---------------------------------------------------------------------------
// Histogram crossing search (verified r1-r3)
// ---------------------------------------------------------------------------
__device__ __forceinline__ void find_crossing(int* hist, int* grp, int target,
                                              int* s_bin, int* s_chi) {
    const int t = threadIdx.x;
    const int b0 = hist[4*t], b1 = hist[4*t+1], b2 = hist[4*t+2], b3 = hist[4*t+3];
    grp[t] = b0 + b1 + b2 + b3;
    __syncthreads();
    for (int off = 1; off < 256; off <<= 1) {
        int add = (t + off < 256) ? grp[t + off] : 0;
        __syncthreads();
        grp[t] += add;
        __syncthreads();
    }
    int cab = (t < 255) ? grp[t + 1] : 0;
    const int hb[4] = {b0, b1, b2, b3};
    #pragma unroll
    for (int i = 3; i >= 0; i--) {
        const int h = hb[i];
        if (cab < target && cab + h >= target) { *s_bin = 4*t + i; *s_chi = cab; }
        cab += h;
    }
    __syncthreads();
}

// ---------------------------------------------------------------------------
// Fast-path top-512 lse over pruned candidates (one block per row).
// ---------------------------------------------------------------------------
__global__ void __launch_bounds__(256) topk_lse_cand(const float* __restrict__ cand,
                                                     const int* __restrict__ cnt,
                                                     const int* __restrict__ qcnt,
                                                     const int* __restrict__ labels,
                                                     float* __restrict__ lseq) {
    const int row = blockIdx.x, t = threadIdx.x;
    const int ccraw = cnt[row * 16];
    const int cc    = min(ccraw, CAP_);
    const int opp   = opp_of(labels[row], qcnt);
    if (!(opp >= HARD_K_ && ccraw <= CAP_ && cc >= HARD_K_)) return;  // fallback handles

    __shared__ float cb[CAP_];
    __shared__ int hist[1024];
    __shared__ int grp[256];
    __shared__ int s_bin, s_chi;
    __shared__ float scf[4]; __shared__ int sci[4];

    const float* rowp = cand + (size_t)row * CAP_;
    float mloc = -1e30f;
    for (int k = t; k < cc; k += 256) { const float v = rowp[k]; cb[k] = v; mloc = fmaxf(mloc, v); }
    for (int k = t; k < 1024; k += 256) hist[k] = 0;
    #pragma unroll
    for (int o = 32; o > 0; o >>= 1) mloc = fmaxf(mloc, __shfl_xor(mloc, o));
    if ((t & 63) == 0) scf[t >> 6] = mloc;
    __syncthreads();
    const float m = fmaxf(fmaxf(scf[0], scf[1]), fmaxf(scf[2], scf[3]));

    const float LO = PRETHR - 1e-4f;
    const float range = fmaxf(m - LO, 1e-6f);
    const float scale = 1024.0f / range;
    for (int k = t; k < cc; k += 256) {
        const int b = (int)fminf(fmaxf((cb[k] - LO) * scale, 0.0f), 1023.0f);
        atomicAdd(&hist[b], 1);
    }
    __syncthreads();
    find_crossing(hist, grp, HARD_K_, &s_bin, &s_chi);
    const float thr = LO + s_bin * (range * (1.0f / 1024.0f));

    float sl = 0.0f; int cg = 0;
    for (int k = t; k < cc; k += 256) {
        const float v = cb[k];
        if (v > thr) { cg++; sl += __expf((v - m) * INV_T); }
    }
    #pragma unroll
    for (int o = 32; o > 0; o >>= 1) { sl += __shfl_xor(sl, o); cg += __shfl_xor(cg, o); }
    if ((t & 63) == 0) { scf[t >> 6] = sl; sci[t >> 6] = cg; }
    __syncthreads();
    if (t == 0) {
        const float slt = scf[0] + scf[1] + scf[2] + scf[3];
        const int   cgt = sci[0] + sci[1] + sci[2] + sci[3];
        const float sadj = slt + ((float)HARD_K_ - (float)cgt) * __expf((thr - m) * INV_T);
        lseq[row] = m * INV_T + __logf(sadj);
    }
}

// iterate all 128 packed-half2 values
#define FOR_ALL_VALS(BODY)                                                   \
    _Pragma("unroll")                                                        \
    for (int _k = 0; _k < 64; _k++) {                                        \
        const float2 _f = __half22float2(*(const __half2*)&dv[_k]);          \
        { const float v = _f.x; BODY }                                       \
        { const float v = _f.y; BODY }                                       \
    }

// ---------------------------------------------------------------------------
// Exact fallback for rows the fast path can't handle (normally zero rows):
// recompute the sims row, then (a) opp==0: lse over raw first 512,
// (b) 0<opp<512: lse over all opp, (c) else: r3-verified register select.
// ---------------------------------------------------------------------------
__global__ void __launch_bounds__(256) topk_lse_fallback(const short* __restrict__ zb,
                                                         const short* __restrict__ qb,
                                                         const int* __restrict__ labels,
                                                         const int* __restrict__ qlab,
                                                         const int* __restrict__ qcnt,
                                                         const int* __restrict__ cnt,
                                                         float* __restrict__ lseq) {
    const int row = blockIdx.x, t = threadIdx.x;
    const int ccraw = cnt[row * 16];
    const int cc    = min(ccraw, CAP_);
    const int opp   = opp_of(labels[row], qcnt);
    if (opp >= HARD_K_ && ccraw <= CAP_ && cc >= HARD_K_) return;   // fast path did it

    __shared__ float zrow[128];
    __shared__ int hist[1024];
    __shared__ int grp[256];
    __shared__ int s_bin, s_chi, s_bin2, s_chi2;
    __shared__ float scf[4]; __shared__ int sci[4];
    if (t < 128) zrow[t] = bf2f(zb[(size_t)row * 128 + t]);
    __syncthreads();

    const int mylab = labels[row];
    unsigned dv[64];
    float rm = -1e30f, rs = 0.0f;          // raw online lse for j<512 (scaled by 1/T)
    for (int k = 0; k < 128; k++) {
        const int j = t + 256 * k;
        float d = 0.0f;
        #pragma unroll
        for (int c = 0; c < 16; ++c) {
            const short8 qv = *(const short8*)(qb + (size_t)j * 128 + c * 8);
            #pragma unroll
            for (int e = 0; e < 8; ++e) d += zrow[c * 8 + e] * bf2f(qv[e]);
        }
        if (j < HARD_K_) {
            const float sv = d * INV_T;
            if (sv > rm) { rs = rs * __expf(rm - sv) + 1.0f; rm = sv; }
            else         { rs += __expf(sv - rm); }
        }
        const int q = qlab[j];
        const float mv = (q != mylab && q >= 0) ? d : -65504.0f;
        const __half h = __float2half(mv);
        unsigned short* p = (unsigned short*)&dv[k >> 1];
        p[k & 1] = *(const unsigned short*)&h;
    }

    if (opp == 0) {
        // block-merge (rm, rs)
        #pragma unroll
        for (int o = 32; o > 0; o >>= 1) {
            const float om = __shfl_xor(rm, o), os = __shfl_xor(rs, o);
            const float nm = fmaxf(rm, om);
            rs = rs * __expf(rm - nm) + os * __expf(om - nm);
            rm = nm;
        }
        if ((t & 63) == 0) { scf[t >> 6] = rm; ((float*)sci)[t >> 6] = rs; }
        __syncthreads();
        if (t == 0) {
            float M = -1e30f, Sx = 0.0f;
            for (int w = 0; w < 4; w++) {
                const float nm = fmaxf(M, scf[w]);
                Sx = Sx * __expf(M - nm) + ((float*)sci)[w] * __expf(scf[w] - nm);
                M = nm;
            }
            lseq[row] = M + __logf(Sx);
        }
        return;
    }
    if (opp < HARD_K_) {
        float mm = -1e30f, ss = 0.0f;
        FOR_ALL_VALS(
            if (v > -60000.0f) {
                const float sv = v * INV_T;
                if (sv > mm) { ss = ss * __expf(mm - sv) + 1.0f; mm = sv; }
                else         { ss += __expf(sv - mm); }
            } )
        #pragma unroll
        for (int o = 32; o > 0; o >>= 1) {
            const float om = __shfl_xor(mm, o), os = __shfl_xor(ss, o);
            const float nm = fmaxf(mm, om);
            ss = ss * __expf(mm - nm) + os * __expf(om - nm);
            mm = nm;
        }
        if ((t & 63) == 0) { scf[t >> 6] = mm; ((float*)sci)[t >> 6] = ss; }
        __syncthreads();
        if (t == 0) {
            float M = -1e30f, Sx = 0.0f;
            for (int w = 0; w < 4; w++) {
                const float nm = fmaxf(M, scf[w]);
                Sx = Sx * __expf(M - nm) + ((float*)sci)[w] * __expf(scf[w] - nm);
                M = nm;
            }
            lseq[row] = M + __logf(Sx);
        }
        return;
    }

    // full register select (r3-verified structure)
    float mloc = -1e30f;
    FOR_ALL_VALS( mloc = fmaxf(mloc, v); )
    #pragma unroll
    for (int o = 32; o > 0; o >>= 1) mloc = fmaxf(mloc, __shfl_xor(mloc, o));
    if ((t & 63) == 0) scf[t >> 6] = mloc;
    __syncthreads();
    const float m = fmaxf(fmaxf(scf[0], scf[1]), fmaxf(scf[2], scf[3]));

    int c1 = 0, c2 = 0;
    const float w1 = m - 0.25f, w2 = m - 1.0f;
    FOR_ALL_VALS( c1 += (v >= w1); c2 += (v >= w2); )
    #pragma unroll
    for (int o = 32; o > 0; o >>= 1) { c1 += __shfl_xor(c1, o); c2 += __shfl_xor(c2, o); }
    if ((t & 63) == 0) { sci[t >> 6] = c1; }
    __syncthreads();
    const int C1 = sci[0] + sci[1] + sci[2] + sci[3];
    if ((t & 63) == 0) { sci[t >> 6] = c2; }
    __syncthreads();
    const int C2 = sci[0] + sci[1] + sci[2] + sci[3];

    float lo;
    if      (C1 >= HARD_K_) lo = w1;
    else if (C2 >= HARD_K_) lo = w2;
    else                    lo = -1.01f;
    const float range = m - lo;
    const float scale = 1024.0f / range;

    for (int k = t; k < 1024; k += 256) hist[k] = 0;
    __syncthreads();
    FOR_ALL_VALS(
        if (v >= lo) {
            const float bf = fminf((v - lo) * scale, 1023.0f);
            atomicAdd(&hist[(int)bf], 1);
        } )
    __syncthreads();
    find_crossing(hist, grp, HARD_K_, &s_bin, &s_chi);
    const int   bin1 = s_bin, chi1 = s_chi;
    const float binw = range * (1.0f / 1024.0f);
    const float lo1  = lo + bin1 * binw;
    const float ssc  = 1024.0f / binw;

    for (int k = t; k < 1024; k += 256) hist[k] = 0;
    __syncthreads();
    FOR_ALL_VALS(
        if (v >= lo) {
            const float bf = fminf((v - lo) * scale, 1023.0f);
            if ((int)bf == bin1) {
                const float sf = fminf(fmaxf((v - lo1) * ssc, 0.0f), 1023.0f);
                atomicAdd(&hist[(int)sf], 1);
            }
        } )
    __syncthreads();
    find_crossing(hist, grp, HARD_K_ - chi1, &s_bin2, &s_chi2);
    const float thr = lo1 + s_bin2 * (binw * (1.0f / 1024.0f));

    float sl = 0.0f; int cg = 0;
    FOR_ALL_VALS( if (v > thr) { cg++; sl += __expf((v - m) * INV_T); } )
    #pragma unroll
    for (int o = 32; o > 0; o >>= 1) { sl += __shfl_xor(sl, o); cg += __shfl_xor(cg, o); }
    if ((t & 63) == 0) { scf[t >> 6] = sl; sci[t >> 6] = cg; }
    __syncthreads();
    if (t == 0) {
        const float slt = scf[0] + scf[1] + scf[2] + scf[3];
        const int   cgt = sci[0] + sci[1] + sci[2] + sci[3];
        const float sadj = slt + ((float)HARD_K_ - (float)cgt) * __expf((thr - m) * INV_T);
        lseq[row] = m * INV_T + __logf(sadj);
    }
}

// ---------------------------------------------------------------------------
// Per-row batch lse + positive-pair loss (verified r1-r3)
// ---------------------------------------------------------------------------
__global__ void __launch_bounds__(256) batch_row_loss(const float* __restrict__ S,
                                                      const int* __restrict__ labels,
                                                      const float* __restrict__ lse_queue,
                                                      float* __restrict__ loss_sum,
                                                      unsigned int* __restrict__ pair_count) {
    const int row = blockIdx.x, t = threadIdx.x;
    __shared__ int lab[BATCH_N];
    __shared__ float wm[4], wsum[4], Lsh;
    __shared__ float rp[4]; __shared__ int rc[4];
    for (int k = t; k < BATCH_N; k += 256) lab[k] = labels[k];
    __syncthreads();
    const int myLab = lab[row];
    const float* rowp = S + (size_t)row * BATCH_N;

    float v[8];
    float mm = -1e30f, ss = 0.0f;
    #pragma unroll
    for (int k = 0; k < 8; k++) {
        const int j = t + 256 * k;
        v[k] = rowp[j] * INV_T;
        if (lab[j] != myLab) {
            const float sv = v[k];
            if (sv > mm) { ss = ss * __expf(mm - sv) + 1.0f; mm = sv; }
            else         { ss += __expf(sv - mm); }
        }
    }
    #pragma unroll
    for (int o = 32; o > 0; o >>= 1) {
        const float om = __shfl_xor(mm, o), os = __shfl_xor(ss, o);
        const float nm = fmaxf(mm, om);
        ss = ss * __expf(mm - nm) + os * __expf(om - nm);
        mm = nm;
    }
    if ((t & 63) == 0) { wm[t >> 6] = mm; wsum[t >> 6] = ss; }
    __syncthreads();
    if (t == 0) {
        float M = -1e30f, Sx = 0.0f;
        for (int w = 0; w < 4; w++) {
            const float nm = fmaxf(M, wm[w]);
            Sx = Sx * __expf(M - nm) + wsum[w] * __expf(wm[w] - nm);
            M = nm;
        }
        const float lseb = (Sx > 0.0f) ? M + __logf(Sx) : -1e30f;
        const float Lq = lse_queue[row];
        const float mx = fmaxf(lseb, Lq), mn = fminf(lseb, Lq);
        Lsh = mx + log1pf(__expf(mn - mx));
    }
    __syncthreads();
    const float L = Lsh;

    float part = 0.0f; int cnt = 0;
    #pragma unroll
    for (int k = 0; k < 8; k++) {
        const int j = t + 256 * k;
        if (lab[j] == myLab && j != row) {
            const float sv = v[k];
            const float mx = fmaxf(sv, L), mn = fminf(sv, L);
            part += (mx + log1pf(__expf(mn - mx))) - sv;
            cnt++;
        }
    }
    #pragma unroll
    for (int o = 32; o > 0; o >>= 1) { part += __shfl_xor(part, o); cnt += __shfl_xor(cnt, o); }
    if ((t & 63) == 0) { rp[t >> 6] = part; rc[t >> 6] = cnt; }
    __syncthreads();
    if (t == 0) {
        atomicAdd(loss_sum, rp[0] + rp[1] + rp[2] + rp[3]);
        atomicAdd(pair_count, (unsigned int)(rc[0] + rc[1] + rc[2] + rc[3]));
    }
}

__global__ void finalize_loss(const float* __restrict__ loss_sum,
                              const unsigned int* __restrict__ cnt,
                              float* __restrict__ out) {
    if (blockIdx.x == 0 && threadIdx.x == 0) {
        const unsigned int c = *cnt;
        out[0] = (c > 0) ? (*loss_sum / (float)c) : 0.0f;
    }
}

// ---------------------------------------------------------------------------
extern "C" void kernel_launch(void* const* d_in, const int* in_sizes, int n_in,
                              void* d_out, int out_size, void* d_ws, size_t ws_size,
                              hipStream_t stream) {
    const float* emb    = (const float*)d_in[0];
    const int*   labels = (const int*)  d_in[1];
    const float* W1     = (const float*)d_in[2];
    const float* b1     = (const float*)d_in[3];
    const float* W2     = (const float*)d_in[4];
    const float* b2     = (const float*)d_in[5];
    const float* queue  = (const float*)d_in[6];
    const int*   qlab   = (const int*)  d_in[7];

    char* ws = (char*)d_ws;
    float* cand = (float*)(ws);                          // 2048*8192*4 = 67108864
    float* Sbuf = (float*)(ws + 67108864);               // 16777216
    short* embb = (short*)(ws + 83886080);               // 3145728
    short* hbf  = (short*)(ws + 87031808);               // 3145728
    float* z    = (float*)(ws + 90177536);               // 1048576
    short* zb   = (short*)(ws + 91226112);               // 524288
    short* qb   = (short*)(ws + 91750400);               // 8388608
    short* w1t  = (short*)(ws + 100139008);              // 1179648
    short* w2t  = (short*)(ws + 101318656);              // 196608
    float* lseq = (float*)(ws + 101515264);              // 8192
    int*   cnt  = (int*)  (ws + 101523456);              // 2048*16*4 = 131072 (padded)
    int*   qcnt = (int*)  (ws + 101654528);              // 16
    float*        accf = (float*)       (ws + 101654544);
    unsigned int* accc = (unsigned int*)(ws + 101654548);

    hipMemsetAsync(ws + 101523456, 0, 131072 + 16 + 8, stream);

    dim3 blk(256);
    cast_bf16_vec<<<dim3(BATCH_N * EMB_D_ / 4 / 256), blk, 0, stream>>>(emb, embb, BATCH_N * EMB_D_ / 4);
    cast_bf16_vec<<<dim3(QUEUE_N * PROJ_D_ / 4 / 256), blk, 0, stream>>>(queue, qb, QUEUE_N * PROJ_D_ / 4);
    transpose_cast<<<dim3(EMB_D_ / 64, EMB_D_ / 64), blk, 0, stream>>>(W1, w1t, EMB_D_, EMB_D_);
    transpose_cast<<<dim3(PROJ_D_ / 64, EMB_D_ / 64), blk, 0, stream>>>(W2, w2t, EMB_D_, PROJ_D_);
    count_qlab<<<dim3(32), blk, 0, stream>>>(qlab, qcnt);
    mfma_nt_k<short, true ><<<dim3(EMB_D_ / 128, BATCH_N / 128), blk, 0, stream>>>(embb, w1t, b1, hbf, EMB_D_, EMB_D_);
    mfma_nt_k<float, false><<<dim3(PROJ_D_ / 128, BATCH_N / 128), blk, 0, stream>>>(hbf, w2t, b2, z, PROJ_D_, EMB_D_);
    normalize_cast<<<BATCH_N, PROJ_D_, 0, stream>>>(z, zb);
    mfma_nt_prune<<<dim3(QUEUE_N / 128, BATCH_N / 128), blk, 0, stream>>>(zb, qb, cand, cnt, labels, qlab);
    topk_lse_cand<<<BATCH_N, 256, 0, stream>>>(cand, cnt, qcnt, labels, lseq);
    topk_lse_fallback<<<BATCH_N, 256, 0, stream>>>(zb, qb, labels, qlab, qcnt, cnt, lseq);
    mfma_nt_plain<<<dim3(BATCH_N / 128, BATCH_N / 128), blk, 0, stream>>>(zb, zb, Sbuf, BATCH_N);
    batch_row_loss<<<BATCH_N, 256, 0, stream>>>(Sbuf, labels, lseq, accf, accc);
    finalize_loss<<<1, 64, 0, stream>>>(accf, accc, (float*)d_out);
}

// Round 5
// 270.634 us; speedup vs baseline: 2.1310x; 2.1310x over previous
//
#include <hip/hip_runtime.h>
#include <hip/hip_fp16.h>

#define BATCH_N   2048
#define EMB_D_    768
#define PROJ_D_   128
#define QUEUE_N   32768
#define HARD_K_   512
static constexpr float INV_T = 1.0f / 0.07f;
static constexpr float WLO   = 0.12f;    // stream-hist window low (512th opp val ~0.164)

typedef __attribute__((ext_vector_type(8))) short short8;
typedef __attribute__((ext_vector_type(4))) short short4v;
typedef __attribute__((ext_vector_type(4))) float f32x4;

__device__ __forceinline__ unsigned short f2bf(float f) {
    unsigned u = __float_as_uint(f);
    unsigned r = u + 0x7fffu + ((u >> 16) & 1u);   // RNE
    return (unsigned short)(r >> 16);
}
__device__ __forceinline__ float bf2f(short s) {
    return __uint_as_float(((unsigned)(unsigned short)s) << 16);
}
__device__ __forceinline__ int opp_of(int mylab, const int* __restrict__ qcnt) {
    const int same = (mylab == 0) ? qcnt[0] : ((mylab == 1) ? qcnt[1] : 0);
    return qcnt[2] - same;
}

// ---------------------------------------------------------------------------
// bf16 MFMA NT GEMM, K=128 in LDS (verified r2/r3). MASK: fp16 store with
// same/invalid-label -> -65504; else raw fp32 store.
// ---------------------------------------------------------------------------
template<typename OutT, bool MASK>
__global__ void __launch_bounds__(256) mfma_nt(const short* __restrict__ Ab,
                                               const short* __restrict__ Bb,
                                               OutT* __restrict__ C, int N,
                                               const int* __restrict__ labA,
                                               const int* __restrict__ labB) {
    __shared__ __align__(16) short As[128 * 128];
    __shared__ __align__(16) short Bs[128 * 128];
    const int t = threadIdx.x;
    const int lane = t & 63, wv = t >> 6;
    const int l16 = lane & 15, l4 = lane >> 4;
    const int m0 = blockIdx.y * 128, n0 = blockIdx.x * 128;

    #pragma unroll
    for (int it = 0; it < 8; ++it) {
        const int r = it * 4 + wv, row = r * 4 + l4, cg = l16 ^ (row & 15);
        __builtin_amdgcn_global_load_lds(
            (const __attribute__((address_space(1))) void*)(Ab + (size_t)(m0 + row) * 128 + cg * 8),
            (__attribute__((address_space(3))) void*)(As + r * 512), 16, 0, 0);
    }
    #pragma unroll
    for (int it = 0; it < 8; ++it) {
        const int r = it * 4 + wv, row = r * 4 + l4, cg = l16 ^ (row & 15);
        __builtin_amdgcn_global_load_lds(
            (const __attribute__((address_space(1))) void*)(Bb + (size_t)(n0 + row) * 128 + cg * 8),
            (__attribute__((address_space(3))) void*)(Bs + r * 512), 16, 0, 0);
    }
    __syncthreads();

    const int wm = (wv & 1) * 64, wn = (wv >> 1) * 64;
    f32x4 acc[4][4];
    #pragma unroll
    for (int i = 0; i < 4; ++i)
        #pragma unroll
        for (int j = 0; j < 4; ++j) acc[i][j] = f32x4{0.f, 0.f, 0.f, 0.f};

    #pragma unroll
    for (int ks = 0; ks < 4; ++ks) {
        short8 af[4], bfr[4];
        const int ch = (ks * 4 + l4) ^ l16;
        #pragma unroll
        for (int i = 0; i < 4; ++i) {
            af[i]  = *(const short8*)(As + (wm + i * 16 + l16) * 128 + ch * 8);
            bfr[i] = *(const short8*)(Bs + (wn + i * 16 + l16) * 128 + ch * 8);
        }
        #pragma unroll
        for (int i = 0; i < 4; ++i)
            #pragma unroll
            for (int j = 0; j < 4; ++j)
                acc[i][j] = __builtin_amdgcn_mfma_f32_16x16x32_bf16(af[i], bfr[j], acc[i][j], 0, 0, 0);
    }

    int qn[4];
    if constexpr (MASK) {
        #pragma unroll
        for (int j = 0; j < 4; ++j) qn[j] = labB[n0 + wn + j * 16 + l16];
    }
    #pragma unroll
    for (int i = 0; i < 4; ++i) {
        #pragma unroll
        for (int r = 0; r < 4; ++r) {
            const int m = m0 + wm + i * 16 + l4 * 4 + r;
            if constexpr (MASK) {
                const int lm = labA[m];
                #pragma unroll
                for (int j = 0; j < 4; ++j) {
                    const int n = n0 + wn + j * 16 + l16;
                    const float v = (qn[j] != lm && qn[j] >= 0) ? acc[i][j][r] : -65504.0f;
                    ((__half*)C)[(size_t)m * N + n] = __float2half(v);
                }
            } else {
                #pragma unroll
                for (int j = 0; j < 4; ++j) {
                    const int n = n0 + wn + j * 16 + l16;
                    ((float*)C)[(size_t)m * N + n] = acc[i][j][r];
                }
            }
        }
    }
}

// ---------------------------------------------------------------------------
// bf16 MFMA NT GEMM with K-loop, fused bias(+ReLU). Verified r3/r4 (MLP).
// ---------------------------------------------------------------------------
template<typename OutT, bool RELU>
__global__ void __launch_bounds__(256) mfma_nt_k(const short* __restrict__ Ab,
                                                 const short* __restrict__ Bb,
                                                 const float* __restrict__ bias,
                                                 OutT* __restrict__ C,
                                                 int N, int K) {
    __shared__ __align__(16) short As[128 * 128];
    __shared__ __align__(16) short Bs[128 * 128];
    const int t = threadIdx.x;
    const int lane = t & 63, wv = t >> 6;
    const int l16 = lane & 15, l4 = lane >> 4;
    const int m0 = blockIdx.y * 128, n0 = blockIdx.x * 128;
    const int wm = (wv & 1) * 64, wn = (wv >> 1) * 64;

    f32x4 acc[4][4];
    #pragma unroll
    for (int i = 0; i < 4; ++i)
        #pragma unroll
        for (int j = 0; j < 4; ++j) acc[i][j] = f32x4{0.f, 0.f, 0.f, 0.f};

    for (int kb = 0; kb < K; kb += 128) {
        __syncthreads();
        #pragma unroll
        for (int it = 0; it < 8; ++it) {
            const int r = it * 4 + wv, row = r * 4 + l4, cg = l16 ^ (row & 15);
            __builtin_amdgcn_global_load_lds(
                (const __attribute__((address_space(1))) void*)(Ab + (size_t)(m0 + row) * K + kb + cg * 8),
                (__attribute__((address_space(3))) void*)(As + r * 512), 16, 0, 0);
        }
        #pragma unroll
        for (int it = 0; it < 8; ++it) {
            const int r = it * 4 + wv, row = r * 4 + l4, cg = l16 ^ (row & 15);
            __builtin_amdgcn_global_load_lds(
                (const __attribute__((address_space(1))) void*)(Bb + (size_t)(n0 + row) * K + kb + cg * 8),
                (__attribute__((address_space(3))) void*)(Bs + r * 512), 16, 0, 0);
        }
        __syncthreads();
        #pragma unroll
        for (int ks = 0; ks < 4; ++ks) {
            short8 af[4], bfr[4];
            const int ch = (ks * 4 + l4) ^ l16;
            #pragma unroll
            for (int i = 0; i < 4; ++i) {
                af[i]  = *(const short8*)(As + (wm + i * 16 + l16) * 128 + ch * 8);
                bfr[i] = *(const short8*)(Bs + (wn + i * 16 + l16) * 128 + ch * 8);
            }
            #pragma unroll
            for (int i = 0; i < 4; ++i)
                #pragma unroll
                for (int j = 0; j < 4; ++j)
                    acc[i][j] = __builtin_amdgcn_mfma_f32_16x16x32_bf16(af[i], bfr[j], acc[i][j], 0, 0, 0);
        }
    }

    float bsv[4];
    #pragma unroll
    for (int j = 0; j < 4; ++j) bsv[j] = bias[n0 + wn + j * 16 + l16];
    #pragma unroll
    for (int i = 0; i < 4; ++i)
        #pragma unroll
        for (int r = 0; r < 4; ++r) {
            const int m = m0 + wm + i * 16 + l4 * 4 + r;
            #pragma unroll
            for (int j = 0; j < 4; ++j) {
                const int n = n0 + wn + j * 16 + l16;
                float v = acc[i][j][r] + bsv[j];
                if (RELU) v = fmaxf(v, 0.0f);
                if constexpr (sizeof(OutT) == 2) ((short*)C)[(size_t)m * N + n] = (short)f2bf(v);
                else                             ((float*)C)[(size_t)m * N + n] = v;
            }
        }
}

// ---------------------------------------------------------------------------
__global__ void __launch_bounds__(256) transpose_cast(const float* __restrict__ A,
                                                      short* __restrict__ At,
                                                      int R, int C) {
    __shared__ float tile[64][65];
    const int bx = blockIdx.x * 64, by = blockIdx.y * 64;
    const int t = threadIdx.x, tc = t & 63, tg = t >> 6;
    #pragma unroll
    for (int i = 0; i < 16; i++) {
        const int r = tg * 16 + i;
        tile[r][tc] = A[(size_t)(by + r) * C + bx + tc];
    }
    __syncthreads();
    #pragma unroll
    for (int i = 0; i < 16; i++) {
        const int r = tg * 16 + i;
        At[(size_t)(bx + r) * R + by + tc] = (short)f2bf(tile[tc][r]);
    }
}

__global__ void normalize_cast(const float* __restrict__ z, short* __restrict__ zb) {
    const int row = blockIdx.x, t = threadIdx.x;
    const float v = z[(size_t)row * PROJ_D_ + t];
    float ss = v * v;
    #pragma unroll
    for (int o = 32; o > 0; o >>= 1) ss += __shfl_down(ss, o);
    __shared__ float s2[2];
    if ((t & 63) == 0) s2[t >> 6] = ss;
    __syncthreads();
    zb[(size_t)row * PROJ_D_ + t] = (short)f2bf(v / sqrtf(s2[0] + s2[1]));
}

__global__ void cast_bf16_vec(const float* __restrict__ src, short* __restrict__ dst, int n4) {
    const int i = blockIdx.x * blockDim.x + threadIdx.x;
    if (i < n4) {
        const float4 f = ((const float4*)src)[i];
        short4v o = {(short)f2bf(f.x), (short)f2bf(f.y), (short)f2bf(f.z), (short)f2bf(f.w)};
        ((short4v*)dst)[i] = o;
    }
}

// queue-label census: qcnt[0]=#{==0}, qcnt[1]=#{==1}, qcnt[2]=#{>=0}
__global__ void count_qlab(const int* __restrict__ qlab, int* __restrict__ qcnt) {
    const int i = blockIdx.x * 256 + threadIdx.x;
    int c0 = 0, c1 = 0, cv = 0;
    for (int j = i; j < QUEUE_N; j += 8192) {
        const int q = qlab[j];
        c0 += (q == 0); c1 += (q == 1); cv += (q >= 0);
    }
    #pragma unroll
    for (int o = 32; o > 0; o >>= 1) {
        c0 += __shfl_xor(c0, o); c1 += __shfl_xor(c1, o); cv += __shfl_xor(cv, o);
    }
    if ((threadIdx.x & 63) == 0) {
        atomicAdd(&qcnt[0], c0); atomicAdd(&qcnt[1], c1); atomicAdd(&qcnt[2], cv);
    }
}

// ---------------------------------------------------------------------------
// Histogram crossing search (verified r1-r4)
// ---------------------------------------------------------------------------
__device__ __forceinline__ void find_crossing(int* hist, int* grp, int target,
                                              int* s_bin, int* s_chi) {
    const int t = threadIdx.x;
    const int b0 = hist[4*t], b1 = hist[4*t+1], b2 = hist[4*t+2], b3 = hist[4*t+3];
    grp[t] = b0 + b1 + b2 + b3;
    __syncthreads();
    for (int off = 1; off < 256; off <<= 1) {
        int add = (t + off < 256) ? grp[t + off] : 0;
        __syncthreads();
        grp[t] += add;
        __syncthreads();
    }
    int cab = (t < 255) ? grp[t + 1] : 0;
    const int hb[4] = {b0, b1, b2, b3};
    #pragma unroll
    for (int i = 3; i >= 0; i--) {
        const int h = hb[i];
        if (cab < target && cab + h >= target) { *s_bin = 4*t + i; *s_chi = cab; }
        cab += h;
    }
    __syncthreads();
}

// ---------------------------------------------------------------------------
// Single-pass streaming top-512 lse. One block per row. Fixed window
// [WLO, 1.0], 1024 bins; count-hist + expsum-hist (ref point 1.0). The lse
// is composed from exact per-bin exp sums above the crossing bin plus a
// proportional share of the crossing bin (bin width 0.00086 -> <=1.3% error
// on boundary terms only). Rows not handleable -> flag=0, exact fallback.
// ---------------------------------------------------------------------------
__global__ void __launch_bounds__(256) topk_lse_stream(const __half* __restrict__ sims,
                                                       const int* __restrict__ qcnt,
                                                       const int* __restrict__ labels,
                                                       float* __restrict__ lseq,
                                                       int* __restrict__ flag) {
    const int row = blockIdx.x, t = threadIdx.x;
    const uint4* rowp = (const uint4*)(sims + (size_t)row * QUEUE_N);
    __shared__ int   hist[1024];
    __shared__ float fexp[1024];
    __shared__ int   grp[256];
    __shared__ int   s_bin, s_chi;
    __shared__ float scf[4];

    for (int k = t; k < 1024; k += 256) { hist[k] = 0; fexp[k] = 0.0f; }
    __syncthreads();

    const float scale = 1024.0f / (1.0f - WLO);
    #pragma unroll 4
    for (int k = 0; k < 16; k++) {
        const uint4 u = rowp[k * 256 + t];
        const __half2* hp = (const __half2*)&u;
        #pragma unroll
        for (int q = 0; q < 4; q++) {
            const float2 f = __half22float2(hp[q]);
            #pragma unroll
            for (int e = 0; e < 2; e++) {
                const float v = e ? f.y : f.x;
                if (v >= WLO) {
                    const int b = min((int)((v - WLO) * scale), 1023);
                    atomicAdd(&hist[b], 1);
                    atomicAdd(&fexp[b], __expf((v - 1.0f) * INV_T));
                }
            }
        }
    }
    __syncthreads();

    // suffix-sum of counts; total in grp[0]
    const int b0 = hist[4*t], b1 = hist[4*t+1], b2 = hist[4*t+2], b3 = hist[4*t+3];
    grp[t] = b0 + b1 + b2 + b3;
    __syncthreads();
    for (int off = 1; off < 256; off <<= 1) {
        int add = (t + off < 256) ? grp[t + off] : 0;
        __syncthreads();
        grp[t] += add;
        __syncthreads();
    }
    const int total = grp[0];
    const int opp   = opp_of(labels[row], qcnt);
    if (total < HARD_K_ || opp < HARD_K_) {           // block-uniform
        if (t == 0) flag[row] = 0;
        return;
    }
    // crossing bin
    {
        int cab = (t < 255) ? grp[t + 1] : 0;
        const int hb[4] = {b0, b1, b2, b3};
        #pragma unroll
        for (int i = 3; i >= 0; i--) {
            const int h = hb[i];
            if (cab < HARD_K_ && cab + h >= HARD_K_) { s_bin = 4*t + i; s_chi = cab; }
            cab += h;
        }
    }
    __syncthreads();
    const int bin1 = s_bin, cab1 = s_chi;

    // sum exp-bins strictly above bin1
    float fs = 0.0f;
    #pragma unroll
    for (int i = 0; i < 4; i++) {
        const int idx = 4*t + i;
        if (idx > bin1) fs += fexp[idx];
    }
    #pragma unroll
    for (int o = 32; o > 0; o >>= 1) fs += __shfl_xor(fs, o);
    if ((t & 63) == 0) scf[t >> 6] = fs;
    __syncthreads();
    if (t == 0) {
        const float Sabove = scf[0] + scf[1] + scf[2] + scf[3];
        const int   take   = HARD_K_ - cab1;
        const float sadj   = Sabove + fexp[bin1] * ((float)take / (float)hist[bin1]);
        lseq[row] = INV_T + __logf(sadj);
        flag[row] = 1;
    }
}

// iterate all 128 packed-half2 values
#define FOR_ALL_VALS(BODY)                                                   \
    _Pragma("unroll")                                                        \
    for (int _k = 0; _k < 64; _k++) {                                        \
        const float2 _f = __half22float2(*(const __half2*)&dv[_k]);          \
        { const float v = _f.x; BODY }                                       \
        { const float v = _f.y; BODY }                                       \
    }

// ---------------------------------------------------------------------------
// Exact fallback for rows the stream path can't handle (normally zero rows).
// Recomputes the sims row from zb/qb: (a) opp==0: lse over raw first 512,
// (b) 0<opp<512: lse over all opp, (c) else: r3-verified register select.
// ---------------------------------------------------------------------------
__global__ void __launch_bounds__(256) topk_lse_fallback(const short* __restrict__ zb,
                                                         const short* __restrict__ qb,
                                                         const int* __restrict__ labels,
                                                         const int* __restrict__ qlab,
                                                         const int* __restrict__ qcnt,
                                                         const int* __restrict__ flag,
                                                         float* __restrict__ lseq) {
    const int row = blockIdx.x, t = threadIdx.x;
    if (flag[row]) return;                     // stream path handled it
    const int opp = opp_of(labels[row], qcnt);

    __shared__ float zrow[128];
    __shared__ int hist[1024];
    __shared__ int grp[256];
    __shared__ int s_bin, s_chi, s_bin2, s_chi2;
    __shared__ float scf[4]; __shared__ int sci[4];
    if (t < 128) zrow[t] = bf2f(zb[(size_t)row * 128 + t]);
    __syncthreads();

    const int mylab = labels[row];
    unsigned dv[64];
    float rm = -1e30f, rs = 0.0f;              // raw online lse for j<512
    for (int k = 0; k < 128; k++) {
        const int j = t + 256 * k;
        float d = 0.0f;
        #pragma unroll
        for (int c = 0; c < 16; ++c) {
            const short8 qv = *(const short8*)(qb + (size_t)j * 128 + c * 8);
            #pragma unroll
            for (int e = 0; e < 8; ++e) d += zrow[c * 8 + e] * bf2f(qv[e]);
        }
        if (j < HARD_K_) {
            const float sv = d * INV_T;
            if (sv > rm) { rs = rs * __expf(rm - sv) + 1.0f; rm = sv; }
            else         { rs += __expf(sv - rm); }
        }
        const int q = qlab[j];
        const float mv = (q != mylab && q >= 0) ? d : -65504.0f;
        const __half h = __float2half(mv);
        unsigned short* p = (unsigned short*)&dv[k >> 1];
        p[k & 1] = *(const unsigned short*)&h;
    }

    if (opp == 0) {
        #pragma unroll
        for (int o = 32; o > 0; o >>= 1) {
            const float om = __shfl_xor(rm, o), os = __shfl_xor(rs, o);
            const float nm = fmaxf(rm, om);
            rs = rs * __expf(rm - nm) + os * __expf(om - nm);
            rm = nm;
        }
        if ((t & 63) == 0) { scf[t >> 6] = rm; ((float*)sci)[t >> 6] = rs; }
        __syncthreads();
        if (t == 0) {
            float M = -1e30f, Sx = 0.0f;
            for (int w = 0; w < 4; w++) {
                const float nm = fmaxf(M, scf[w]);
                Sx = Sx * __expf(M - nm) + ((float*)sci)[w] * __expf(scf[w] - nm);
                M = nm;
            }
            lseq[row] = M + __logf(Sx);
        }
        return;
    }
    if (opp < HARD_K_) {
        float mm = -1e30f, ss = 0.0f;
        FOR_ALL_VALS(
            if (v > -60000.0f) {
                const float sv = v * INV_T;
                if (sv > mm) { ss = ss * __expf(mm - sv) + 1.0f; mm = sv; }
                else         { ss += __expf(sv - mm); }
            } )
        #pragma unroll
        for (int o = 32; o > 0; o >>= 1) {
            const float om = __shfl_xor(mm, o), os = __shfl_xor(ss, o);
            const float nm = fmaxf(mm, om);
            ss = ss * __expf(mm - nm) + os * __expf(om - nm);
            mm = nm;
        }
        if ((t & 63) == 0) { scf[t >> 6] = mm; ((float*)sci)[t >> 6] = ss; }
        __syncthreads();
        if (t == 0) {
            float M = -1e30f, Sx = 0.0f;
            for (int w = 0; w < 4; w++) {
                const float nm = fmaxf(M, scf[w]);
                Sx = Sx * __expf(M - nm) + ((float*)sci)[w] * __expf(scf[w] - nm);
                M = nm;
            }
            lseq[row] = M + __logf(Sx);
        }
        return;
    }

    // full register select (r3-verified structure)
    float mloc = -1e30f;
    FOR_ALL_VALS( mloc = fmaxf(mloc, v); )
    #pragma unroll
    for (int o = 32; o > 0; o >>= 1) mloc = fmaxf(mloc, __shfl_xor(mloc, o));
    if ((t & 63) == 0) scf[t >> 6] = mloc;
    __syncthreads();
    const float m = fmaxf(fmaxf(scf[0], scf[1]), fmaxf(scf[2], scf[3]));

    int c1 = 0, c2 = 0;
    const float w1 = m - 0.25f, w2 = m - 1.0f;
    FOR_ALL_VALS( c1 += (v >= w1); c2 += (v >= w2); )
    #pragma unroll
    for (int o = 32; o > 0; o >>= 1) { c1 += __shfl_xor(c1, o); c2 += __shfl_xor(c2, o); }
    if ((t & 63) == 0) { sci[t >> 6] = c1; }
    __syncthreads();
    const int C1 = sci[0] + sci[1] + sci[2] + sci[3];
    __syncthreads();
    if ((t & 63) == 0) { sci[t >> 6] = c2; }
    __syncthreads();
    const int C2 = sci[0] + sci[1] + sci[2] + sci[3];

    float lo;
    if      (C1 >= HARD_K_) lo = w1;
    else if (C2 >= HARD_K_) lo = w2;
    else                    lo = -1.01f;
    const float range = m - lo;
    const float scale = 1024.0f / range;

    for (int k = t; k < 1024; k += 256) hist[k] = 0;
    __syncthreads();
    FOR_ALL_VALS(
        if (v >= lo) {
            const float bf = fminf((v - lo) * scale, 1023.0f);
            atomicAdd(&hist[(int)bf], 1);
        } )
    __syncthreads();
    find_crossing(hist, grp, HARD_K_, &s_bin, &s_chi);
    const int   bin1 = s_bin, chi1 = s_chi;
    const float binw = range * (1.0f / 1024.0f);
    const float lo1  = lo + bin1 * binw;
    const float ssc  = 1024.0f / binw;

    for (int k = t; k < 1024; k += 256) hist[k] = 0;
    __syncthreads();
    FOR_ALL_VALS(
        if (v >= lo) {
            const float bf = fminf((v - lo) * scale, 1023.0f);
            if ((int)bf == bin1) {
                const float sf = fminf(fmaxf((v - lo1) * ssc, 0.0f), 1023.0f);
                atomicAdd(&hist[(int)sf], 1);
            }
        } )
    __syncthreads();
    find_crossing(hist, grp, HARD_K_ - chi1, &s_bin2, &s_chi2);
    const float thr = lo1 + s_bin2 * (binw * (1.0f / 1024.0f));

    float sl = 0.0f; int cg = 0;
    FOR_ALL_VALS( if (v > thr) { cg++; sl += __expf((v - m) * INV_T); } )
    #pragma unroll
    for (int o = 32; o > 0; o >>= 1) { sl += __shfl_xor(sl, o); cg += __shfl_xor(cg, o); }
    if ((t & 63) == 0) { scf[t >> 6] = sl; sci[t >> 6] = cg; }
    __syncthreads();
    if (t == 0) {
        const float slt = scf[0] + scf[1] + scf[2] + scf[3];
        const int   cgt = sci[0] + sci[1] + sci[2] + sci[3];
        const float sadj = slt + ((float)HARD_K_ - (float)cgt) * __expf((thr - m) * INV_T);
        lseq[row] = m * INV_T + __logf(sadj);
    }
}

// ---------------------------------------------------------------------------
// Per-row batch lse + positive-pair loss (verified r1-r4)
// ---------------------------------------------------------------------------
__global__ void __launch_bounds__(256) batch_row_loss(const float* __restrict__ S,
                                                      const int* __restrict__ labels,
                                                      const float* __restrict__ lse_queue,
                                                      float* __restrict__ loss_sum,
                                                      unsigned int* __restrict__ pair_count) {
    const int row = blockIdx.x, t = threadIdx.x;
    __shared__ int lab[BATCH_N];
    __shared__ float wm[4], wsum[4], Lsh;
    __shared__ float rp[4]; __shared__ int rc[4];
    for (int k = t; k < BATCH_N; k += 256) lab[k] = labels[k];
    __syncthreads();
    const int myLab = lab[row];
    const float* rowp = S + (size_t)row * BATCH_N;

    float v[8];
    float mm = -1e30f, ss = 0.0f;
    #pragma unroll
    for (int k = 0; k < 8; k++) {
        const int j = t + 256 * k;
        v[k] = rowp[j] * INV_T;
        if (lab[j] != myLab) {
            const float sv = v[k];
            if (sv > mm) { ss = ss * __expf(mm - sv) + 1.0f; mm = sv; }
            else         { ss += __expf(sv - mm); }
        }
    }
    #pragma unroll
    for (int o = 32; o > 0; o >>= 1) {
        const float om = __shfl_xor(mm, o), os = __shfl_xor(ss, o);
        const float nm = fmaxf(mm, om);
        ss = ss * __expf(mm - nm) + os * __expf(om - nm);
        mm = nm;
    }
    if ((t & 63) == 0) { wm[t >> 6] = mm; wsum[t >> 6] = ss; }
    __syncthreads();
    if (t == 0) {
        float M = -1e30f, Sx = 0.0f;
        for (int w = 0; w < 4; w++) {
            const float nm = fmaxf(M, wm[w]);
            Sx = Sx * __expf(M - nm) + wsum[w] * __expf(wm[w] - nm);
            M = nm;
        }
        const float lseb = (Sx > 0.0f) ? M + __logf(Sx) : -1e30f;
        const float Lq = lse_queue[row];
        const float mx = fmaxf(lseb, Lq), mn = fminf(lseb, Lq);
        Lsh = mx + log1pf(__expf(mn - mx));
    }
    __syncthreads();
    const float L = Lsh;

    float part = 0.0f; int cnt = 0;
    #pragma unroll
    for (int k = 0; k < 8; k++) {
        const int j = t + 256 * k;
        if (lab[j] == myLab && j != row) {
            const float sv = v[k];
            const float mx = fmaxf(sv, L), mn = fminf(sv, L);
            part += (mx + log1pf(__expf(mn - mx))) - sv;
            cnt++;
        }
    }
    #pragma unroll
    for (int o = 32; o > 0; o >>= 1) { part += __shfl_xor(part, o); cnt += __shfl_xor(cnt, o); }
    if ((t & 63) == 0) { rp[t >> 6] = part; rc[t >> 6] = cnt; }
    __syncthreads();
    if (t == 0) {
        atomicAdd(loss_sum, rp[0] + rp[1] + rp[2] + rp[3]);
        atomicAdd(pair_count, (unsigned int)(rc[0] + rc[1] + rc[2] + rc[3]));
    }
}

__global__ void finalize_loss(const float* __restrict__ loss_sum,
                              const unsigned int* __restrict__ cnt,
                              float* __restrict__ out) {
    if (blockIdx.x == 0 && threadIdx.x == 0) {
        const unsigned int c = *cnt;
        out[0] = (c > 0) ? (*loss_sum / (float)c) : 0.0f;
    }
}

// ---------------------------------------------------------------------------
extern "C" void kernel_launch(void* const* d_in, const int* in_sizes, int n_in,
                              void* d_out, int out_size, void* d_ws, size_t ws_size,
                              hipStream_t stream) {
    const float* emb    = (const float*)d_in[0];
    const int*   labels = (const int*)  d_in[1];
    const float* W1     = (const float*)d_in[2];
    const float* b1     = (const float*)d_in[3];
    const float* W2     = (const float*)d_in[4];
    const float* b2     = (const float*)d_in[5];
    const float* queue  = (const float*)d_in[6];
    const int*   qlab   = (const int*)  d_in[7];

    char* ws = (char*)d_ws;
    __half* simsq = (__half*)(ws);                       // [0, 134217728)
    float*  Sbuf  = (float*) (ws);                       // overlays simsq post-topk
    short*  embb  = (short*) (ws + 134217728);           // 3145728
    short*  hbf   = (short*) (ws + 137363456);           // 3145728
    float*  z     = (float*) (ws + 140509184);           // 1048576
    short*  zb    = (short*) (ws + 141557760);           // 524288
    short*  qb    = (short*) (ws + 142082048);           // 8388608
    short*  w1t   = (short*) (ws + 150470656);           // 1179648
    short*  w2t   = (short*) (ws + 151650304);           // 196608
    float*  lseq  = (float*) (ws + 151846912);           // 8192
    int*    flag  = (int*)   (ws + 151855104);           // 8192
    int*    qcnt  = (int*)   (ws + 151863296);           // 64
    float*        accf = (float*)       (ws + 151863360);
    unsigned int* accc = (unsigned int*)(ws + 151863364);

    hipMemsetAsync(ws + 151855104, 0, 8192 + 64 + 8, stream);

    dim3 blk(256);
    cast_bf16_vec<<<dim3(BATCH_N * EMB_D_ / 4 / 256), blk, 0, stream>>>(emb, embb, BATCH_N * EMB_D_ / 4);
    cast_bf16_vec<<<dim3(QUEUE_N * PROJ_D_ / 4 / 256), blk, 0, stream>>>(queue, qb, QUEUE_N * PROJ_D_ / 4);
    transpose_cast<<<dim3(EMB_D_ / 64, EMB_D_ / 64), blk, 0, stream>>>(W1, w1t, EMB_D_, EMB_D_);
    transpose_cast<<<dim3(PROJ_D_ / 64, EMB_D_ / 64), blk, 0, stream>>>(W2, w2t, EMB_D_, PROJ_D_);
    count_qlab<<<dim3(32), blk, 0, stream>>>(qlab, qcnt);
    mfma_nt_k<short, true ><<<dim3(EMB_D_ / 128, BATCH_N / 128), blk, 0, stream>>>(embb, w1t, b1, hbf, EMB_D_, EMB_D_);
    mfma_nt_k<float, false><<<dim3(PROJ_D_ / 128, BATCH_N / 128), blk, 0, stream>>>(hbf, w2t, b2, z, PROJ_D_, EMB_D_);
    normalize_cast<<<BATCH_N, PROJ_D_, 0, stream>>>(z, zb);
    mfma_nt<__half, true><<<dim3(QUEUE_N / 128, BATCH_N / 128), blk, 0, stream>>>(
        zb, qb, simsq, QUEUE_N, labels, qlab);
    topk_lse_stream<<<BATCH_N, 256, 0, stream>>>(simsq, qcnt, labels, lseq, flag);
    topk_lse_fallback<<<BATCH_N, 256, 0, stream>>>(zb, qb, labels, qlab, qcnt, flag, lseq);
    mfma_nt<float, false><<<dim3(BATCH_N / 128, BATCH_N / 128), blk, 0, stream>>>(
        zb, zb, Sbuf, BATCH_N, nullptr, nullptr);
    batch_row_loss<<<BATCH_N, 256, 0, stream>>>(Sbuf, labels, lseq, accf, accc);
    finalize_loss<<<1, 64, 0, stream>>>(accf, accc, (float*)d_out);
}

// Round 6
// 267.303 us; speedup vs baseline: 2.1575x; 1.0125x over previous
//
#include <hip/hip_runtime.h>
#include <hip/hip_fp16.h>

#define BATCH_N   2048
#define EMB_D_    768
#define PROJ_D_   128
#define QUEUE_N   32768
#define HARD_K_   512
static constexpr float INV_T = 1.0f / 0.07f;
static constexpr float WLO   = 0.12f;    // stream-hist window low (512th opp val ~0.164)

typedef __attribute__((ext_vector_type(8))) short short8;
typedef __attribute__((ext_vector_type(4))) short short4v;
typedef __attribute__((ext_vector_type(4))) float f32x4;

__device__ __forceinline__ unsigned short f2bf(float f) {
    unsigned u = __float_as_uint(f);
    unsigned r = u + 0x7fffu + ((u >> 16) & 1u);   // RNE
    return (unsigned short)(r >> 16);
}
__device__ __forceinline__ float bf2f(short s) {
    return __uint_as_float(((unsigned)(unsigned short)s) << 16);
}
__device__ __forceinline__ int opp_of(int mylab, const int* __restrict__ qcnt) {
    const int same = (mylab == 0) ? qcnt[0] : ((mylab == 1) ? qcnt[1] : 0);
    return qcnt[2] - same;
}

// ---------------------------------------------------------------------------
// bf16 MFMA NT GEMM, K=128 in LDS (verified r2-r5). MASK: fp16 store with
// same/invalid-label -> -65504; else raw fp32 store.
// ---------------------------------------------------------------------------
template<typename OutT, bool MASK>
__global__ void __launch_bounds__(256) mfma_nt(const short* __restrict__ Ab,
                                               const short* __restrict__ Bb,
                                               OutT* __restrict__ C, int N,
                                               const int* __restrict__ labA,
                                               const int* __restrict__ labB) {
    __shared__ __align__(16) short As[128 * 128];
    __shared__ __align__(16) short Bs[128 * 128];
    const int t = threadIdx.x;
    const int lane = t & 63, wv = t >> 6;
    const int l16 = lane & 15, l4 = lane >> 4;
    const int m0 = blockIdx.y * 128, n0 = blockIdx.x * 128;

    #pragma unroll
    for (int it = 0; it < 8; ++it) {
        const int r = it * 4 + wv, row = r * 4 + l4, cg = l16 ^ (row & 15);
        __builtin_amdgcn_global_load_lds(
            (const __attribute__((address_space(1))) void*)(Ab + (size_t)(m0 + row) * 128 + cg * 8),
            (__attribute__((address_space(3))) void*)(As + r * 512), 16, 0, 0);
    }
    #pragma unroll
    for (int it = 0; it < 8; ++it) {
        const int r = it * 4 + wv, row = r * 4 + l4, cg = l16 ^ (row & 15);
        __builtin_amdgcn_global_load_lds(
            (const __attribute__((address_space(1))) void*)(Bb + (size_t)(n0 + row) * 128 + cg * 8),
            (__attribute__((address_space(3))) void*)(Bs + r * 512), 16, 0, 0);
    }
    __syncthreads();

    const int wm = (wv & 1) * 64, wn = (wv >> 1) * 64;
    f32x4 acc[4][4];
    #pragma unroll
    for (int i = 0; i < 4; ++i)
        #pragma unroll
        for (int j = 0; j < 4; ++j) acc[i][j] = f32x4{0.f, 0.f, 0.f, 0.f};

    #pragma unroll
    for (int ks = 0; ks < 4; ++ks) {
        short8 af[4], bfr[4];
        const int ch = (ks * 4 + l4) ^ l16;
        #pragma unroll
        for (int i = 0; i < 4; ++i) {
            af[i]  = *(const short8*)(As + (wm + i * 16 + l16) * 128 + ch * 8);
            bfr[i] = *(const short8*)(Bs + (wn + i * 16 + l16) * 128 + ch * 8);
        }
        #pragma unroll
        for (int i = 0; i < 4; ++i)
            #pragma unroll
            for (int j = 0; j < 4; ++j)
                acc[i][j] = __builtin_amdgcn_mfma_f32_16x16x32_bf16(af[i], bfr[j], acc[i][j], 0, 0, 0);
    }

    int qn[4];
    if constexpr (MASK) {
        #pragma unroll
        for (int j = 0; j < 4; ++j) qn[j] = labB[n0 + wn + j * 16 + l16];
    }
    #pragma unroll
    for (int i = 0; i < 4; ++i) {
        #pragma unroll
        for (int r = 0; r < 4; ++r) {
            const int m = m0 + wm + i * 16 + l4 * 4 + r;
            if constexpr (MASK) {
                const int lm = labA[m];
                #pragma unroll
                for (int j = 0; j < 4; ++j) {
                    const int n = n0 + wn + j * 16 + l16;
                    const float v = (qn[j] != lm && qn[j] >= 0) ? acc[i][j][r] : -65504.0f;
                    ((__half*)C)[(size_t)m * N + n] = __float2half(v);
                }
            } else {
                #pragma unroll
                for (int j = 0; j < 4; ++j) {
                    const int n = n0 + wn + j * 16 + l16;
                    ((float*)C)[(size_t)m * N + n] = acc[i][j][r];
                }
            }
        }
    }
}

// ---------------------------------------------------------------------------
// bf16 MFMA NT GEMM with K-loop, fused bias(+ReLU). Verified r3-r5 (MLP).
// ---------------------------------------------------------------------------
template<typename OutT, bool RELU>
__global__ void __launch_bounds__(256) mfma_nt_k(const short* __restrict__ Ab,
                                                 const short* __restrict__ Bb,
                                                 const float* __restrict__ bias,
                                                 OutT* __restrict__ C,
                                                 int N, int K) {
    __shared__ __align__(16) short As[128 * 128];
    __shared__ __align__(16) short Bs[128 * 128];
    const int t = threadIdx.x;
    const int lane = t & 63, wv = t >> 6;
    const int l16 = lane & 15, l4 = lane >> 4;
    const int m0 = blockIdx.y * 128, n0 = blockIdx.x * 128;
    const int wm = (wv & 1) * 64, wn = (wv >> 1) * 64;

    f32x4 acc[4][4];
    #pragma unroll
    for (int i = 0; i < 4; ++i)
        #pragma unroll
        for (int j = 0; j < 4; ++j) acc[i][j] = f32x4{0.f, 0.f, 0.f, 0.f};

    for (int kb = 0; kb < K; kb += 128) {
        __syncthreads();
        #pragma unroll
        for (int it = 0; it < 8; ++it) {
            const int r = it * 4 + wv, row = r * 4 + l4, cg = l16 ^ (row & 15);
            __builtin_amdgcn_global_load_lds(
                (const __attribute__((address_space(1))) void*)(Ab + (size_t)(m0 + row) * K + kb + cg * 8),
                (__attribute__((address_space(3))) void*)(As + r * 512), 16, 0, 0);
        }
        #pragma unroll
        for (int it = 0; it < 8; ++it) {
            const int r = it * 4 + wv, row = r * 4 + l4, cg = l16 ^ (row & 15);
            __builtin_amdgcn_global_load_lds(
                (const __attribute__((address_space(1))) void*)(Bb + (size_t)(n0 + row) * K + kb + cg * 8),
                (__attribute__((address_space(3))) void*)(Bs + r * 512), 16, 0, 0);
        }
        __syncthreads();
        #pragma unroll
        for (int ks = 0; ks < 4; ++ks) {
            short8 af[4], bfr[4];
            const int ch = (ks * 4 + l4) ^ l16;
            #pragma unroll
            for (int i = 0; i < 4; ++i) {
                af[i]  = *(const short8*)(As + (wm + i * 16 + l16) * 128 + ch * 8);
                bfr[i] = *(const short8*)(Bs + (wn + i * 16 + l16) * 128 + ch * 8);
            }
            #pragma unroll
            for (int i = 0; i < 4; ++i)
                #pragma unroll
                for (int j = 0; j < 4; ++j)
                    acc[i][j] = __builtin_amdgcn_mfma_f32_16x16x32_bf16(af[i], bfr[j], acc[i][j], 0, 0, 0);
        }
    }

    float bsv[4];
    #pragma unroll
    for (int j = 0; j < 4; ++j) bsv[j] = bias[n0 + wn + j * 16 + l16];
    #pragma unroll
    for (int i = 0; i < 4; ++i)
        #pragma unroll
        for (int r = 0; r < 4; ++r) {
            const int m = m0 + wm + i * 16 + l4 * 4 + r;
            #pragma unroll
            for (int j = 0; j < 4; ++j) {
                const int n = n0 + wn + j * 16 + l16;
                float v = acc[i][j][r] + bsv[j];
                if (RELU) v = fmaxf(v, 0.0f);
                if constexpr (sizeof(OutT) == 2) ((short*)C)[(size_t)m * N + n] = (short)f2bf(v);
                else                             ((float*)C)[(size_t)m * N + n] = v;
            }
        }
}

// ---------------------------------------------------------------------------
__global__ void __launch_bounds__(256) transpose_cast(const float* __restrict__ A,
                                                      short* __restrict__ At,
                                                      int R, int C) {
    __shared__ float tile[64][65];
    const int bx = blockIdx.x * 64, by = blockIdx.y * 64;
    const int t = threadIdx.x, tc = t & 63, tg = t >> 6;
    #pragma unroll
    for (int i = 0; i < 16; i++) {
        const int r = tg * 16 + i;
        tile[r][tc] = A[(size_t)(by + r) * C + bx + tc];
    }
    __syncthreads();
    #pragma unroll
    for (int i = 0; i < 16; i++) {
        const int r = tg * 16 + i;
        At[(size_t)(bx + r) * R + by + tc] = (short)f2bf(tile[tc][r]);
    }
}

__global__ void normalize_cast(const float* __restrict__ z, short* __restrict__ zb) {
    const int row = blockIdx.x, t = threadIdx.x;
    const float v = z[(size_t)row * PROJ_D_ + t];
    float ss = v * v;
    #pragma unroll
    for (int o = 32; o > 0; o >>= 1) ss += __shfl_down(ss, o);
    __shared__ float s2[2];
    if ((t & 63) == 0) s2[t >> 6] = ss;
    __syncthreads();
    zb[(size_t)row * PROJ_D_ + t] = (short)f2bf(v / sqrtf(s2[0] + s2[1]));
}

__global__ void cast_bf16_vec(const float* __restrict__ src, short* __restrict__ dst, int n4) {
    const int i = blockIdx.x * blockDim.x + threadIdx.x;
    if (i < n4) {
        const float4 f = ((const float4*)src)[i];
        short4v o = {(short)f2bf(f.x), (short)f2bf(f.y), (short)f2bf(f.z), (short)f2bf(f.w)};
        ((short4v*)dst)[i] = o;
    }
}

// queue-label census: qcnt[0]=#{==0}, qcnt[1]=#{==1}, qcnt[2]=#{>=0}
__global__ void count_qlab(const int* __restrict__ qlab, int* __restrict__ qcnt) {
    const int i = blockIdx.x * 256 + threadIdx.x;
    int c0 = 0, c1 = 0, cv = 0;
    for (int j = i; j < QUEUE_N; j += 8192) {
        const int q = qlab[j];
        c0 += (q == 0); c1 += (q == 1); cv += (q >= 0);
    }
    #pragma unroll
    for (int o = 32; o > 0; o >>= 1) {
        c0 += __shfl_xor(c0, o); c1 += __shfl_xor(c1, o); cv += __shfl_xor(cv, o);
    }
    if ((threadIdx.x & 63) == 0) {
        atomicAdd(&qcnt[0], c0); atomicAdd(&qcnt[1], c1); atomicAdd(&qcnt[2], cv);
    }
}

// ---------------------------------------------------------------------------
// Histogram crossing search (verified r1-r5)
// ---------------------------------------------------------------------------
__device__ __forceinline__ void find_crossing(int* hist, int* grp, int target,
                                              int* s_bin, int* s_chi) {
    const int t = threadIdx.x;
    const int b0 = hist[4*t], b1 = hist[4*t+1], b2 = hist[4*t+2], b3 = hist[4*t+3];
    grp[t] = b0 + b1 + b2 + b3;
    __syncthreads();
    for (int off = 1; off < 256; off <<= 1) {
        int add = (t + off < 256) ? grp[t + off] : 0;
        __syncthreads();
        grp[t] += add;
        __syncthreads();
    }
    int cab = (t < 255) ? grp[t + 1] : 0;
    const int hb[4] = {b0, b1, b2, b3};
    #pragma unroll
    for (int i = 3; i >= 0; i--) {
        const int h = hb[i];
        if (cab < target && cab + h >= target) { *s_bin = 4*t + i; *s_chi = cab; }
        cab += h;
    }
    __syncthreads();
}

// ---------------------------------------------------------------------------
// Single-pass streaming top-512 lse (verified r5). One block per row.
// ---------------------------------------------------------------------------
__global__ void __launch_bounds__(256) topk_lse_stream(const __half* __restrict__ sims,
                                                       const int* __restrict__ qcnt,
                                                       const int* __restrict__ labels,
                                                       float* __restrict__ lseq,
                                                       int* __restrict__ flag) {
    const int row = blockIdx.x, t = threadIdx.x;
    const uint4* rowp = (const uint4*)(sims + (size_t)row * QUEUE_N);
    __shared__ int   hist[1024];
    __shared__ float fexp[1024];
    __shared__ int   grp[256];
    __shared__ int   s_bin, s_chi;
    __shared__ float scf[4];

    for (int k = t; k < 1024; k += 256) { hist[k] = 0; fexp[k] = 0.0f; }
    __syncthreads();

    const float scale = 1024.0f / (1.0f - WLO);
    #pragma unroll 4
    for (int k = 0; k < 16; k++) {
        const uint4 u = rowp[k * 256 + t];
        const __half2* hp = (const __half2*)&u;
        #pragma unroll
        for (int q = 0; q < 4; q++) {
            const float2 f = __half22float2(hp[q]);
            #pragma unroll
            for (int e = 0; e < 2; e++) {
                const float v = e ? f.y : f.x;
                if (v >= WLO) {
                    const int b = min((int)((v - WLO) * scale), 1023);
                    atomicAdd(&hist[b], 1);
                    atomicAdd(&fexp[b], __expf((v - 1.0f) * INV_T));
                }
            }
        }
    }
    __syncthreads();

    const int b0 = hist[4*t], b1 = hist[4*t+1], b2 = hist[4*t+2], b3 = hist[4*t+3];
    grp[t] = b0 + b1 + b2 + b3;
    __syncthreads();
    for (int off = 1; off < 256; off <<= 1) {
        int add = (t + off < 256) ? grp[t + off] : 0;
        __syncthreads();
        grp[t] += add;
        __syncthreads();
    }
    const int total = grp[0];
    const int opp   = opp_of(labels[row], qcnt);
    if (total < HARD_K_ || opp < HARD_K_) {
        if (t == 0) flag[row] = 0;
        return;
    }
    {
        int cab = (t < 255) ? grp[t + 1] : 0;
        const int hb[4] = {b0, b1, b2, b3};
        #pragma unroll
        for (int i = 3; i >= 0; i--) {
            const int h = hb[i];
            if (cab < HARD_K_ && cab + h >= HARD_K_) { s_bin = 4*t + i; s_chi = cab; }
            cab += h;
        }
    }
    __syncthreads();
    const int bin1 = s_bin, cab1 = s_chi;

    float fs = 0.0f;
    #pragma unroll
    for (int i = 0; i < 4; i++) {
        const int idx = 4*t + i;
        if (idx > bin1) fs += fexp[idx];
    }
    #pragma unroll
    for (int o = 32; o > 0; o >>= 1) fs += __shfl_xor(fs, o);
    if ((t & 63) == 0) scf[t >> 6] = fs;
    __syncthreads();
    if (t == 0) {
        const float Sabove = scf[0] + scf[1] + scf[2] + scf[3];
        const int   take   = HARD_K_ - cab1;
        const float sadj   = Sabove + fexp[bin1] * ((float)take / (float)hist[bin1]);
        lseq[row] = INV_T + __logf(sadj);
        flag[row] = 1;
    }
}

// iterate all 128 packed-half2 values
#define FOR_ALL_VALS(BODY)                                                   \
    _Pragma("unroll")                                                        \
    for (int _k = 0; _k < 64; _k++) {                                        \
        const float2 _f = __half22float2(*(const __half2*)&dv[_k]);          \
        { const float v = _f.x; BODY }                                       \
        { const float v = _f.y; BODY }                                       \
    }

// ---------------------------------------------------------------------------
// Exact fallback (verified r5; normally zero rows).
// ---------------------------------------------------------------------------
__global__ void __launch_bounds__(256) topk_lse_fallback(const short* __restrict__ zb,
                                                         const short* __restrict__ qb,
                                                         const int* __restrict__ labels,
                                                         const int* __restrict__ qlab,
                                                         const int* __restrict__ qcnt,
                                                         const int* __restrict__ flag,
                                                         float* __restrict__ lseq) {
    const int row = blockIdx.x, t = threadIdx.x;
    if (flag[row]) return;
    const int opp = opp_of(labels[row], qcnt);

    __shared__ float zrow[128];
    __shared__ int hist[1024];
    __shared__ int grp[256];
    __shared__ int s_bin, s_chi, s_bin2, s_chi2;
    __shared__ float scf[4]; __shared__ int sci[4];
    if (t < 128) zrow[t] = bf2f(zb[(size_t)row * 128 + t]);
    __syncthreads();

    const int mylab = labels[row];
    unsigned dv[64];
    float rm = -1e30f, rs = 0.0f;
    for (int k = 0; k < 128; k++) {
        const int j = t + 256 * k;
        float d = 0.0f;
        #pragma unroll
        for (int c = 0; c < 16; ++c) {
            const short8 qv = *(const short8*)(qb + (size_t)j * 128 + c * 8);
            #pragma unroll
            for (int e = 0; e < 8; ++e) d += zrow[c * 8 + e] * bf2f(qv[e]);
        }
        if (j < HARD_K_) {
            const float sv = d * INV_T;
            if (sv > rm) { rs = rs * __expf(rm - sv) + 1.0f; rm = sv; }
            else         { rs += __expf(sv - rm); }
        }
        const int q = qlab[j];
        const float mv = (q != mylab && q >= 0) ? d : -65504.0f;
        const __half h = __float2half(mv);
        unsigned short* p = (unsigned short*)&dv[k >> 1];
        p[k & 1] = *(const unsigned short*)&h;
    }

    if (opp == 0) {
        #pragma unroll
        for (int o = 32; o > 0; o >>= 1) {
            const float om = __shfl_xor(rm, o), os = __shfl_xor(rs, o);
            const float nm = fmaxf(rm, om);
            rs = rs * __expf(rm - nm) + os * __expf(om - nm);
            rm = nm;
        }
        if ((t & 63) == 0) { scf[t >> 6] = rm; ((float*)sci)[t >> 6] = rs; }
        __syncthreads();
        if (t == 0) {
            float M = -1e30f, Sx = 0.0f;
            for (int w = 0; w < 4; w++) {
                const float nm = fmaxf(M, scf[w]);
                Sx = Sx * __expf(M - nm) + ((float*)sci)[w] * __expf(scf[w] - nm);
                M = nm;
            }
            lseq[row] = M + __logf(Sx);
        }
        return;
    }
    if (opp < HARD_K_) {
        float mm = -1e30f, ss = 0.0f;
        FOR_ALL_VALS(
            if (v > -60000.0f) {
                const float sv = v * INV_T;
                if (sv > mm) { ss = ss * __expf(mm - sv) + 1.0f; mm = sv; }
                else         { ss += __expf(sv - mm); }
            } )
        #pragma unroll
        for (int o = 32; o > 0; o >>= 1) {
            const float om = __shfl_xor(mm, o), os = __shfl_xor(ss, o);
            const float nm = fmaxf(mm, om);
            ss = ss * __expf(mm - nm) + os * __expf(om - nm);
            mm = nm;
        }
        if ((t & 63) == 0) { scf[t >> 6] = mm; ((float*)sci)[t >> 6] = ss; }
        __syncthreads();
        if (t == 0) {
            float M = -1e30f, Sx = 0.0f;
            for (int w = 0; w < 4; w++) {
                const float nm = fmaxf(M, scf[w]);
                Sx = Sx * __expf(M - nm) + ((float*)sci)[w] * __expf(scf[w] - nm);
                M = nm;
            }
            lseq[row] = M + __logf(Sx);
        }
        return;
    }

    float mloc = -1e30f;
    FOR_ALL_VALS( mloc = fmaxf(mloc, v); )
    #pragma unroll
    for (int o = 32; o > 0; o >>= 1) mloc = fmaxf(mloc, __shfl_xor(mloc, o));
    if ((t & 63) == 0) scf[t >> 6] = mloc;
    __syncthreads();
    const float m = fmaxf(fmaxf(scf[0], scf[1]), fmaxf(scf[2], scf[3]));

    int c1 = 0, c2 = 0;
    const float w1 = m - 0.25f, w2 = m - 1.0f;
    FOR_ALL_VALS( c1 += (v >= w1); c2 += (v >= w2); )
    #pragma unroll
    for (int o = 32; o > 0; o >>= 1) { c1 += __shfl_xor(c1, o); c2 += __shfl_xor(c2, o); }
    if ((t & 63) == 0) { sci[t >> 6] = c1; }
    __syncthreads();
    const int C1 = sci[0] + sci[1] + sci[2] + sci[3];
    __syncthreads();
    if ((t & 63) == 0) { sci[t >> 6] = c2; }
    __syncthreads();
    const int C2 = sci[0] + sci[1] + sci[2] + sci[3];

    float lo;
    if      (C1 >= HARD_K_) lo = w1;
    else if (C2 >= HARD_K_) lo = w2;
    else                    lo = -1.01f;
    const float range = m - lo;
    const float scale = 1024.0f / range;

    for (int k = t; k < 1024; k += 256) hist[k] = 0;
    __syncthreads();
    FOR_ALL_VALS(
        if (v >= lo) {
            const float bf = fminf((v - lo) * scale, 1023.0f);
            atomicAdd(&hist[(int)bf], 1);
        } )
    __syncthreads();
    find_crossing(hist, grp, HARD_K_, &s_bin, &s_chi);
    const int   bin1 = s_bin, chi1 = s_chi;
    const float binw = range * (1.0f / 1024.0f);
    const float lo1  = lo + bin1 * binw;
    const float ssc  = 1024.0f / binw;

    for (int k = t; k < 1024; k += 256) hist[k] = 0;
    __syncthreads();
    FOR_ALL_VALS(
        if (v >= lo) {
            const float bf = fminf((v - lo) * scale, 1023.0f);
            if ((int)bf == bin1) {
                const float sf = fminf(fmaxf((v - lo1) * ssc, 0.0f), 1023.0f);
                atomicAdd(&hist[(int)sf], 1);
            }
        } )
    __syncthreads();
    find_crossing(hist, grp, HARD_K_ - chi1, &s_bin2, &s_chi2);
    const float thr = lo1 + s_bin2 * (binw * (1.0f / 1024.0f));

    float sl = 0.0f; int cg = 0;
    FOR_ALL_VALS( if (v > thr) { cg++; sl += __expf((v - m) * INV_T); } )
    #pragma unroll
    for (int o = 32; o > 0; o >>= 1) { sl += __shfl_xor(sl, o); cg += __shfl_xor(cg, o); }
    if ((t & 63) == 0) { scf[t >> 6] = sl; sci[t >> 6] = cg; }
    __syncthreads();
    if (t == 0) {
        const float slt = scf[0] + scf[1] + scf[2] + scf[3];
        const int   cgt = sci[0] + sci[1] + sci[2] + sci[3];
        const float sadj = slt + ((float)HARD_K_ - (float)cgt) * __expf((thr - m) * INV_T);
        lseq[row] = m * INV_T + __logf(sadj);
    }
}

// ---------------------------------------------------------------------------
// Batch lse + positive-pair loss, one WAVE per row (4 rows/block).
// Fixed-reference lse (REF = 1/T, values bounded by |S|<=~1.01/T): no online
// max, 32 independent exps/lane, shuffle-only reductions, 1 barrier.
// ---------------------------------------------------------------------------
__global__ void __launch_bounds__(256) batch_row_loss(const float* __restrict__ S,
                                                      const int* __restrict__ labels,
                                                      const float* __restrict__ lse_queue,
                                                      float* __restrict__ loss_sum,
                                                      unsigned int* __restrict__ pair_count) {
    const int t = threadIdx.x;
    const int wv = t >> 6, lane = t & 63;
    const int row = blockIdx.x * 4 + wv;
    __shared__ int lab[BATCH_N];
    for (int k = t; k < BATCH_N; k += 256) lab[k] = labels[k];
    __syncthreads();
    const int myLab = lab[row];
    const float4* rp4 = (const float4*)(S + (size_t)row * BATCH_N);
    const int4*   lb4 = (const int4*)lab;

    float v[32]; int lb[32];
    #pragma unroll
    for (int kk = 0; kk < 8; kk++) {
        const float4 f = rp4[lane + 64 * kk];
        const int4   l = lb4[lane + 64 * kk];
        v[4*kk+0] = f.x; v[4*kk+1] = f.y; v[4*kk+2] = f.z; v[4*kk+3] = f.w;
        lb[4*kk+0] = l.x; lb[4*kk+1] = l.y; lb[4*kk+2] = l.z; lb[4*kk+3] = l.w;
    }

    // pass A: negatives exp-sum at fixed reference REF = 1/T
    const float REF = INV_T;
    float sneg = 0.0f;
    #pragma unroll
    for (int k = 0; k < 32; k++) {
        const float ev = __expf(v[k] * INV_T - REF);
        sneg += (lb[k] != myLab) ? ev : 0.0f;
    }
    #pragma unroll
    for (int o = 32; o > 0; o >>= 1) sneg += __shfl_xor(sneg, o);
    const float lseb = (sneg > 0.0f) ? REF + __logf(sneg) : -1e30f;
    const float Lq = lse_queue[row];
    const float mx0 = fmaxf(lseb, Lq), mn0 = fminf(lseb, Lq);
    const float L = mx0 + __logf(1.0f + __expf(mn0 - mx0));

    // pass B: positive-pair terms logaddexp(sv, L) - sv
    float part = 0.0f; int cnt = 0;
    #pragma unroll
    for (int k = 0; k < 32; k++) {
        const int j = (lane + 64 * (k >> 2)) * 4 + (k & 3);
        if (lb[k] == myLab && j != row) {
            const float sv = v[k] * INV_T;
            const float mx = fmaxf(sv, L), mn = fminf(sv, L);
            part += (mx - sv) + __logf(1.0f + __expf(mn - mx));
            cnt++;
        }
    }
    #pragma unroll
    for (int o = 32; o > 0; o >>= 1) { part += __shfl_xor(part, o); cnt += __shfl_xor(cnt, o); }
    if (lane == 0) {
        atomicAdd(loss_sum, part);
        atomicAdd(pair_count, (unsigned int)cnt);
    }
}

__global__ void finalize_loss(const float* __restrict__ loss_sum,
                              const unsigned int* __restrict__ cnt,
                              float* __restrict__ out) {
    if (blockIdx.x == 0 && threadIdx.x == 0) {
        const unsigned int c = *cnt;
        out[0] = (c > 0) ? (*loss_sum / (float)c) : 0.0f;
    }
}

// ---------------------------------------------------------------------------
extern "C" void kernel_launch(void* const* d_in, const int* in_sizes, int n_in,
                              void* d_out, int out_size, void* d_ws, size_t ws_size,
                              hipStream_t stream) {
    const float* emb    = (const float*)d_in[0];
    const int*   labels = (const int*)  d_in[1];
    const float* W1     = (const float*)d_in[2];
    const float* b1     = (const float*)d_in[3];
    const float* W2     = (const float*)d_in[4];
    const float* b2     = (const float*)d_in[5];
    const float* queue  = (const float*)d_in[6];
    const int*   qlab   = (const int*)  d_in[7];

    char* ws = (char*)d_ws;
    __half* simsq = (__half*)(ws);                       // [0, 134217728)
    float*  Sbuf  = (float*) (ws);                       // overlays simsq post-topk
    short*  embb  = (short*) (ws + 134217728);           // 3145728
    short*  hbf   = (short*) (ws + 137363456);           // 3145728
    float*  z     = (float*) (ws + 140509184);           // 1048576
    short*  zb    = (short*) (ws + 141557760);           // 524288
    short*  qb    = (short*) (ws + 142082048);           // 8388608
    short*  w1t   = (short*) (ws + 150470656);           // 1179648
    short*  w2t   = (short*) (ws + 151650304);           // 196608
    float*  lseq  = (float*) (ws + 151846912);           // 8192
    int*    flag  = (int*)   (ws + 151855104);           // 8192
    int*    qcnt  = (int*)   (ws + 151863296);           // 64
    float*        accf = (float*)       (ws + 151863360);
    unsigned int* accc = (unsigned int*)(ws + 151863364);

    hipMemsetAsync(ws + 151855104, 0, 8192 + 64 + 8, stream);

    dim3 blk(256);
    cast_bf16_vec<<<dim3(BATCH_N * EMB_D_ / 4 / 256), blk, 0, stream>>>(emb, embb, BATCH_N * EMB_D_ / 4);
    cast_bf16_vec<<<dim3(QUEUE_N * PROJ_D_ / 4 / 256), blk, 0, stream>>>(queue, qb, QUEUE_N * PROJ_D_ / 4);
    transpose_cast<<<dim3(EMB_D_ / 64, EMB_D_ / 64), blk, 0, stream>>>(W1, w1t, EMB_D_, EMB_D_);
    transpose_cast<<<dim3(PROJ_D_ / 64, EMB_D_ / 64), blk, 0, stream>>>(W2, w2t, EMB_D_, PROJ_D_);
    count_qlab<<<dim3(32), blk, 0, stream>>>(qlab, qcnt);
    mfma_nt_k<short, true ><<<dim3(EMB_D_ / 128, BATCH_N / 128), blk, 0, stream>>>(embb, w1t, b1, hbf, EMB_D_, EMB_D_);
    mfma_nt_k<float, false><<<dim3(PROJ_D_ / 128, BATCH_N / 128), blk, 0, stream>>>(hbf, w2t, b2, z, PROJ_D_, EMB_D_);
    normalize_cast<<<BATCH_N, PROJ_D_, 0, stream>>>(z, zb);
    mfma_nt<__half, true><<<dim3(QUEUE_N / 128, BATCH_N / 128), blk, 0, stream>>>(
        zb, qb, simsq, QUEUE_N, labels, qlab);
    topk_lse_stream<<<BATCH_N, 256, 0, stream>>>(simsq, qcnt, labels, lseq, flag);
    topk_lse_fallback<<<BATCH_N, 256, 0, stream>>>(zb, qb, labels, qlab, qcnt, flag, lseq);
    mfma_nt<float, false><<<dim3(BATCH_N / 128, BATCH_N / 128), blk, 0, stream>>>(
        zb, zb, Sbuf, BATCH_N, nullptr, nullptr);
    batch_row_loss<<<BATCH_N / 4, 256, 0, stream>>>(Sbuf, labels, lseq, accf, accc);
    finalize_loss<<<1, 64, 0, stream>>>(accf, accc, (float*)d_out);
}

// Round 7
// 220.501 us; speedup vs baseline: 2.6155x; 1.2123x over previous
//
#include <hip/hip_runtime.h>
#include <hip/hip_fp16.h>

#define BATCH_N   2048
#define EMB_D_    768
#define PROJ_D_   128
#define QUEUE_N   32768
#define HARD_K_   512
static constexpr float INV_T = 1.0f / 0.07f;
static constexpr float WLO   = 0.12f;    // stream-hist window low (512th opp val ~0.164)

typedef __attribute__((ext_vector_type(8))) short short8;
typedef __attribute__((ext_vector_type(4))) short short4v;
typedef __attribute__((ext_vector_type(4))) float f32x4;

__device__ __forceinline__ unsigned short f2bf(float f) {
    unsigned u = __float_as_uint(f);
    unsigned r = u + 0x7fffu + ((u >> 16) & 1u);   // RNE
    return (unsigned short)(r >> 16);
}
__device__ __forceinline__ float bf2f(short s) {
    return __uint_as_float(((unsigned)(unsigned short)s) << 16);
}
__device__ __forceinline__ int opp_of(int mylab, const int* __restrict__ qcnt) {
    const int same = (mylab == 0) ? qcnt[0] : ((mylab == 1) ? qcnt[1] : 0);
    return qcnt[2] - same;
}

// ---------------------------------------------------------------------------
// bf16 MFMA NT GEMM, K=128 in LDS (verified r2-r6). MASK: fp16 store with
// same/invalid-label -> -65504; else raw fp32 store.
// ---------------------------------------------------------------------------
template<typename OutT, bool MASK>
__global__ void __launch_bounds__(256) mfma_nt(const short* __restrict__ Ab,
                                               const short* __restrict__ Bb,
                                               OutT* __restrict__ C, int N,
                                               const int* __restrict__ labA,
                                               const int* __restrict__ labB) {
    __shared__ __align__(16) short As[128 * 128];
    __shared__ __align__(16) short Bs[128 * 128];
    const int t = threadIdx.x;
    const int lane = t & 63, wv = t >> 6;
    const int l16 = lane & 15, l4 = lane >> 4;
    const int m0 = blockIdx.y * 128, n0 = blockIdx.x * 128;

    #pragma unroll
    for (int it = 0; it < 8; ++it) {
        const int r = it * 4 + wv, row = r * 4 + l4, cg = l16 ^ (row & 15);
        __builtin_amdgcn_global_load_lds(
            (const __attribute__((address_space(1))) void*)(Ab + (size_t)(m0 + row) * 128 + cg * 8),
            (__attribute__((address_space(3))) void*)(As + r * 512), 16, 0, 0);
    }
    #pragma unroll
    for (int it = 0; it < 8; ++it) {
        const int r = it * 4 + wv, row = r * 4 + l4, cg = l16 ^ (row & 15);
        __builtin_amdgcn_global_load_lds(
            (const __attribute__((address_space(1))) void*)(Bb + (size_t)(n0 + row) * 128 + cg * 8),
            (__attribute__((address_space(3))) void*)(Bs + r * 512), 16, 0, 0);
    }
    __syncthreads();

    const int wm = (wv & 1) * 64, wn = (wv >> 1) * 64;
    f32x4 acc[4][4];
    #pragma unroll
    for (int i = 0; i < 4; ++i)
        #pragma unroll
        for (int j = 0; j < 4; ++j) acc[i][j] = f32x4{0.f, 0.f, 0.f, 0.f};

    #pragma unroll
    for (int ks = 0; ks < 4; ++ks) {
        short8 af[4], bfr[4];
        const int ch = (ks * 4 + l4) ^ l16;
        #pragma unroll
        for (int i = 0; i < 4; ++i) {
            af[i]  = *(const short8*)(As + (wm + i * 16 + l16) * 128 + ch * 8);
            bfr[i] = *(const short8*)(Bs + (wn + i * 16 + l16) * 128 + ch * 8);
        }
        #pragma unroll
        for (int i = 0; i < 4; ++i)
            #pragma unroll
            for (int j = 0; j < 4; ++j)
                acc[i][j] = __builtin_amdgcn_mfma_f32_16x16x32_bf16(af[i], bfr[j], acc[i][j], 0, 0, 0);
    }

    int qn[4];
    if constexpr (MASK) {
        #pragma unroll
        for (int j = 0; j < 4; ++j) qn[j] = labB[n0 + wn + j * 16 + l16];
    }
    #pragma unroll
    for (int i = 0; i < 4; ++i) {
        #pragma unroll
        for (int r = 0; r < 4; ++r) {
            const int m = m0 + wm + i * 16 + l4 * 4 + r;
            if constexpr (MASK) {
                const int lm = labA[m];
                #pragma unroll
                for (int j = 0; j < 4; ++j) {
                    const int n = n0 + wn + j * 16 + l16;
                    const float v = (qn[j] != lm && qn[j] >= 0) ? acc[i][j][r] : -65504.0f;
                    ((__half*)C)[(size_t)m * N + n] = __float2half(v);
                }
            } else {
                #pragma unroll
                for (int j = 0; j < 4; ++j) {
                    const int n = n0 + wn + j * 16 + l16;
                    ((float*)C)[(size_t)m * N + n] = acc[i][j][r];
                }
            }
        }
    }
}

// ---------------------------------------------------------------------------
// bf16 MFMA NT GEMM with K-loop, fused bias(+ReLU). Verified r3-r6 (MLP).
// ---------------------------------------------------------------------------
template<typename OutT, bool RELU>
__global__ void __launch_bounds__(256) mfma_nt_k(const short* __restrict__ Ab,
                                                 const short* __restrict__ Bb,
                                                 const float* __restrict__ bias,
                                                 OutT* __restrict__ C,
                                                 int N, int K) {
    __shared__ __align__(16) short As[128 * 128];
    __shared__ __align__(16) short Bs[128 * 128];
    const int t = threadIdx.x;
    const int lane = t & 63, wv = t >> 6;
    const int l16 = lane & 15, l4 = lane >> 4;
    const int m0 = blockIdx.y * 128, n0 = blockIdx.x * 128;
    const int wm = (wv & 1) * 64, wn = (wv >> 1) * 64;

    f32x4 acc[4][4];
    #pragma unroll
    for (int i = 0; i < 4; ++i)
        #pragma unroll
        for (int j = 0; j < 4; ++j) acc[i][j] = f32x4{0.f, 0.f, 0.f, 0.f};

    for (int kb = 0; kb < K; kb += 128) {
        __syncthreads();
        #pragma unroll
        for (int it = 0; it < 8; ++it) {
            const int r = it * 4 + wv, row = r * 4 + l4, cg = l16 ^ (row & 15);
            __builtin_amdgcn_global_load_lds(
                (const __attribute__((address_space(1))) void*)(Ab + (size_t)(m0 + row) * K + kb + cg * 8),
                (__attribute__((address_space(3))) void*)(As + r * 512), 16, 0, 0);
        }
        #pragma unroll
        for (int it = 0; it < 8; ++it) {
            const int r = it * 4 + wv, row = r * 4 + l4, cg = l16 ^ (row & 15);
            __builtin_amdgcn_global_load_lds(
                (const __attribute__((address_space(1))) void*)(Bb + (size_t)(n0 + row) * K + kb + cg * 8),
                (__attribute__((address_space(3))) void*)(Bs + r * 512), 16, 0, 0);
        }
        __syncthreads();
        #pragma unroll
        for (int ks = 0; ks < 4; ++ks) {
            short8 af[4], bfr[4];
            const int ch = (ks * 4 + l4) ^ l16;
            #pragma unroll
            for (int i = 0; i < 4; ++i) {
                af[i]  = *(const short8*)(As + (wm + i * 16 + l16) * 128 + ch * 8);
                bfr[i] = *(const short8*)(Bs + (wn + i * 16 + l16) * 128 + ch * 8);
            }
            #pragma unroll
            for (int i = 0; i < 4; ++i)
                #pragma unroll
                for (int j = 0; j < 4; ++j)
                    acc[i][j] = __builtin_amdgcn_mfma_f32_16x16x32_bf16(af[i], bfr[j], acc[i][j], 0, 0, 0);
        }
    }

    float bsv[4];
    #pragma unroll
    for (int j = 0; j < 4; ++j) bsv[j] = bias[n0 + wn + j * 16 + l16];
    #pragma unroll
    for (int i = 0; i < 4; ++i)
        #pragma unroll
        for (int r = 0; r < 4; ++r) {
            const int m = m0 + wm + i * 16 + l4 * 4 + r;
            #pragma unroll
            for (int j = 0; j < 4; ++j) {
                const int n = n0 + wn + j * 16 + l16;
                float v = acc[i][j][r] + bsv[j];
                if (RELU) v = fmaxf(v, 0.0f);
                if constexpr (sizeof(OutT) == 2) ((short*)C)[(size_t)m * N + n] = (short)f2bf(v);
                else                             ((float*)C)[(size_t)m * N + n] = v;
            }
        }
}

// ---------------------------------------------------------------------------
__global__ void __launch_bounds__(256) transpose_cast(const float* __restrict__ A,
                                                      short* __restrict__ At,
                                                      int R, int C) {
    __shared__ float tile[64][65];
    const int bx = blockIdx.x * 64, by = blockIdx.y * 64;
    const int t = threadIdx.x, tc = t & 63, tg = t >> 6;
    #pragma unroll
    for (int i = 0; i < 16; i++) {
        const int r = tg * 16 + i;
        tile[r][tc] = A[(size_t)(by + r) * C + bx + tc];
    }
    __syncthreads();
    #pragma unroll
    for (int i = 0; i < 16; i++) {
        const int r = tg * 16 + i;
        At[(size_t)(bx + r) * R + by + tc] = (short)f2bf(tile[tc][r]);
    }
}

__global__ void normalize_cast(const float* __restrict__ z, short* __restrict__ zb) {
    const int row = blockIdx.x, t = threadIdx.x;
    const float v = z[(size_t)row * PROJ_D_ + t];
    float ss = v * v;
    #pragma unroll
    for (int o = 32; o > 0; o >>= 1) ss += __shfl_down(ss, o);
    __shared__ float s2[2];
    if ((t & 63) == 0) s2[t >> 6] = ss;
    __syncthreads();
    zb[(size_t)row * PROJ_D_ + t] = (short)f2bf(v / sqrtf(s2[0] + s2[1]));
}

__global__ void cast_bf16_vec(const float* __restrict__ src, short* __restrict__ dst, int n4) {
    const int i = blockIdx.x * blockDim.x + threadIdx.x;
    if (i < n4) {
        const float4 f = ((const float4*)src)[i];
        short4v o = {(short)f2bf(f.x), (short)f2bf(f.y), (short)f2bf(f.z), (short)f2bf(f.w)};
        ((short4v*)dst)[i] = o;
    }
}

// queue-label census: qcnt[0]=#{==0}, qcnt[1]=#{==1}, qcnt[2]=#{>=0}
__global__ void count_qlab(const int* __restrict__ qlab, int* __restrict__ qcnt) {
    const int i = blockIdx.x * 256 + threadIdx.x;
    int c0 = 0, c1 = 0, cv = 0;
    for (int j = i; j < QUEUE_N; j += 8192) {
        const int q = qlab[j];
        c0 += (q == 0); c1 += (q == 1); cv += (q >= 0);
    }
    #pragma unroll
    for (int o = 32; o > 0; o >>= 1) {
        c0 += __shfl_xor(c0, o); c1 += __shfl_xor(c1, o); cv += __shfl_xor(cv, o);
    }
    if ((threadIdx.x & 63) == 0) {
        atomicAdd(&qcnt[0], c0); atomicAdd(&qcnt[1], c1); atomicAdd(&qcnt[2], cv);
    }
}

// ---------------------------------------------------------------------------
// Histogram crossing search (verified r1-r6)
// ---------------------------------------------------------------------------
__device__ __forceinline__ void find_crossing(int* hist, int* grp, int target,
                                              int* s_bin, int* s_chi) {
    const int t = threadIdx.x;
    const int b0 = hist[4*t], b1 = hist[4*t+1], b2 = hist[4*t+2], b3 = hist[4*t+3];
    grp[t] = b0 + b1 + b2 + b3;
    __syncthreads();
    for (int off = 1; off < 256; off <<= 1) {
        int add = (t + off < 256) ? grp[t + off] : 0;
        __syncthreads();
        grp[t] += add;
        __syncthreads();
    }
    int cab = (t < 255) ? grp[t + 1] : 0;
    const int hb[4] = {b0, b1, b2, b3};
    #pragma unroll
    for (int i = 3; i >= 0; i--) {
        const int h = hb[i];
        if (cab < target && cab + h >= target) { *s_bin = 4*t + i; *s_chi = cab; }
        cab += h;
    }
    __syncthreads();
}

// ---------------------------------------------------------------------------
// Single-pass streaming top-512 lse (verified r5/r6). One block per row.
// ---------------------------------------------------------------------------
__global__ void __launch_bounds__(256) topk_lse_stream(const __half* __restrict__ sims,
                                                       const int* __restrict__ qcnt,
                                                       const int* __restrict__ labels,
                                                       float* __restrict__ lseq,
                                                       int* __restrict__ flag) {
    const int row = blockIdx.x, t = threadIdx.x;
    const uint4* rowp = (const uint4*)(sims + (size_t)row * QUEUE_N);
    __shared__ int   hist[1024];
    __shared__ float fexp[1024];
    __shared__ int   grp[256];
    __shared__ int   s_bin, s_chi;
    __shared__ float scf[4];

    for (int k = t; k < 1024; k += 256) { hist[k] = 0; fexp[k] = 0.0f; }
    __syncthreads();

    const float scale = 1024.0f / (1.0f - WLO);
    #pragma unroll 4
    for (int k = 0; k < 16; k++) {
        const uint4 u = rowp[k * 256 + t];
        const __half2* hp = (const __half2*)&u;
        #pragma unroll
        for (int q = 0; q < 4; q++) {
            const float2 f = __half22float2(hp[q]);
            #pragma unroll
            for (int e = 0; e < 2; e++) {
                const float v = e ? f.y : f.x;
                if (v >= WLO) {
                    const int b = min((int)((v - WLO) * scale), 1023);
                    atomicAdd(&hist[b], 1);
                    atomicAdd(&fexp[b], __expf((v - 1.0f) * INV_T));
                }
            }
        }
    }
    __syncthreads();

    const int b0 = hist[4*t], b1 = hist[4*t+1], b2 = hist[4*t+2], b3 = hist[4*t+3];
    grp[t] = b0 + b1 + b2 + b3;
    __syncthreads();
    for (int off = 1; off < 256; off <<= 1) {
        int add = (t + off < 256) ? grp[t + off] : 0;
        __syncthreads();
        grp[t] += add;
        __syncthreads();
    }
    const int total = grp[0];
    const int opp   = opp_of(labels[row], qcnt);
    if (total < HARD_K_ || opp < HARD_K_) {
        if (t == 0) flag[row] = 0;
        return;
    }
    {
        int cab = (t < 255) ? grp[t + 1] : 0;
        const int hb[4] = {b0, b1, b2, b3};
        #pragma unroll
        for (int i = 3; i >= 0; i--) {
            const int h = hb[i];
            if (cab < HARD_K_ && cab + h >= HARD_K_) { s_bin = 4*t + i; s_chi = cab; }
            cab += h;
        }
    }
    __syncthreads();
    const int bin1 = s_bin, cab1 = s_chi;

    float fs = 0.0f;
    #pragma unroll
    for (int i = 0; i < 4; i++) {
        const int idx = 4*t + i;
        if (idx > bin1) fs += fexp[idx];
    }
    #pragma unroll
    for (int o = 32; o > 0; o >>= 1) fs += __shfl_xor(fs, o);
    if ((t & 63) == 0) scf[t >> 6] = fs;
    __syncthreads();
    if (t == 0) {
        const float Sabove = scf[0] + scf[1] + scf[2] + scf[3];
        const int   take   = HARD_K_ - cab1;
        const float sadj   = Sabove + fexp[bin1] * ((float)take / (float)hist[bin1]);
        lseq[row] = INV_T + __logf(sadj);
        flag[row] = 1;
    }
}

// iterate all 128 packed-half2 values
#define FOR_ALL_VALS(BODY)                                                   \
    _Pragma("unroll")                                                        \
    for (int _k = 0; _k < 64; _k++) {                                        \
        const float2 _f = __half22float2(*(const __half2*)&dv[_k]);          \
        { const float v = _f.x; BODY }                                       \
        { const float v = _f.y; BODY }                                       \
    }

// ---------------------------------------------------------------------------
// Exact fallback (verified r5/r6; normally zero rows).
// ---------------------------------------------------------------------------
__global__ void __launch_bounds__(256) topk_lse_fallback(const short* __restrict__ zb,
                                                         const short* __restrict__ qb,
                                                         const int* __restrict__ labels,
                                                         const int* __restrict__ qlab,
                                                         const int* __restrict__ qcnt,
                                                         const int* __restrict__ flag,
                                                         float* __restrict__ lseq) {
    const int row = blockIdx.x, t = threadIdx.x;
    if (flag[row]) return;
    const int opp = opp_of(labels[row], qcnt);

    __shared__ float zrow[128];
    __shared__ int hist[1024];
    __shared__ int grp[256];
    __shared__ int s_bin, s_chi, s_bin2, s_chi2;
    __shared__ float scf[4]; __shared__ int sci[4];
    if (t < 128) zrow[t] = bf2f(zb[(size_t)row * 128 + t]);
    __syncthreads();

    const int mylab = labels[row];
    unsigned dv[64];
    float rm = -1e30f, rs = 0.0f;
    for (int k = 0; k < 128; k++) {
        const int j = t + 256 * k;
        float d = 0.0f;
        #pragma unroll
        for (int c = 0; c < 16; ++c) {
            const short8 qv = *(const short8*)(qb + (size_t)j * 128 + c * 8);
            #pragma unroll
            for (int e = 0; e < 8; ++e) d += zrow[c * 8 + e] * bf2f(qv[e]);
        }
        if (j < HARD_K_) {
            const float sv = d * INV_T;
            if (sv > rm) { rs = rs * __expf(rm - sv) + 1.0f; rm = sv; }
            else         { rs += __expf(sv - rm); }
        }
        const int q = qlab[j];
        const float mv = (q != mylab && q >= 0) ? d : -65504.0f;
        const __half h = __float2half(mv);
        unsigned short* p = (unsigned short*)&dv[k >> 1];
        p[k & 1] = *(const unsigned short*)&h;
    }

    if (opp == 0) {
        #pragma unroll
        for (int o = 32; o > 0; o >>= 1) {
            const float om = __shfl_xor(rm, o), os = __shfl_xor(rs, o);
            const float nm = fmaxf(rm, om);
            rs = rs * __expf(rm - nm) + os * __expf(om - nm);
            rm = nm;
        }
        if ((t & 63) == 0) { scf[t >> 6] = rm; ((float*)sci)[t >> 6] = rs; }
        __syncthreads();
        if (t == 0) {
            float M = -1e30f, Sx = 0.0f;
            for (int w = 0; w < 4; w++) {
                const float nm = fmaxf(M, scf[w]);
                Sx = Sx * __expf(M - nm) + ((float*)sci)[w] * __expf(scf[w] - nm);
                M = nm;
            }
            lseq[row] = M + __logf(Sx);
        }
        return;
    }
    if (opp < HARD_K_) {
        float mm = -1e30f, ss = 0.0f;
        FOR_ALL_VALS(
            if (v > -60000.0f) {
                const float sv = v * INV_T;
                if (sv > mm) { ss = ss * __expf(mm - sv) + 1.0f; mm = sv; }
                else         { ss += __expf(sv - mm); }
            } )
        #pragma unroll
        for (int o = 32; o > 0; o >>= 1) {
            const float om = __shfl_xor(mm, o), os = __shfl_xor(ss, o);
            const float nm = fmaxf(mm, om);
            ss = ss * __expf(mm - nm) + os * __expf(om - nm);
            mm = nm;
        }
        if ((t & 63) == 0) { scf[t >> 6] = mm; ((float*)sci)[t >> 6] = ss; }
        __syncthreads();
        if (t == 0) {
            float M = -1e30f, Sx = 0.0f;
            for (int w = 0; w < 4; w++) {
                const float nm = fmaxf(M, scf[w]);
                Sx = Sx * __expf(M - nm) + ((float*)sci)[w] * __expf(scf[w] - nm);
                M = nm;
            }
            lseq[row] = M + __logf(Sx);
        }
        return;
    }

    float mloc = -1e30f;
    FOR_ALL_VALS( mloc = fmaxf(mloc, v); )
    #pragma unroll
    for (int o = 32; o > 0; o >>= 1) mloc = fmaxf(mloc, __shfl_xor(mloc, o));
    if ((t & 63) == 0) scf[t >> 6] = mloc;
    __syncthreads();
    const float m = fmaxf(fmaxf(scf[0], scf[1]), fmaxf(scf[2], scf[3]));

    int c1 = 0, c2 = 0;
    const float w1 = m - 0.25f, w2 = m - 1.0f;
    FOR_ALL_VALS( c1 += (v >= w1); c2 += (v >= w2); )
    #pragma unroll
    for (int o = 32; o > 0; o >>= 1) { c1 += __shfl_xor(c1, o); c2 += __shfl_xor(c2, o); }
    if ((t & 63) == 0) { sci[t >> 6] = c1; }
    __syncthreads();
    const int C1 = sci[0] + sci[1] + sci[2] + sci[3];
    __syncthreads();
    if ((t & 63) == 0) { sci[t >> 6] = c2; }
    __syncthreads();
    const int C2 = sci[0] + sci[1] + sci[2] + sci[3];

    float lo;
    if      (C1 >= HARD_K_) lo = w1;
    else if (C2 >= HARD_K_) lo = w2;
    else                    lo = -1.01f;
    const float range = m - lo;
    const float scale = 1024.0f / range;

    for (int k = t; k < 1024; k += 256) hist[k] = 0;
    __syncthreads();
    FOR_ALL_VALS(
        if (v >= lo) {
            const float bf = fminf((v - lo) * scale, 1023.0f);
            atomicAdd(&hist[(int)bf], 1);
        } )
    __syncthreads();
    find_crossing(hist, grp, HARD_K_, &s_bin, &s_chi);
    const int   bin1 = s_bin, chi1 = s_chi;
    const float binw = range * (1.0f / 1024.0f);
    const float lo1  = lo + bin1 * binw;
    const float ssc  = 1024.0f / binw;

    for (int k = t; k < 1024; k += 256) hist[k] = 0;
    __syncthreads();
    FOR_ALL_VALS(
        if (v >= lo) {
            const float bf = fminf((v - lo) * scale, 1023.0f);
            if ((int)bf == bin1) {
                const float sf = fminf(fmaxf((v - lo1) * ssc, 0.0f), 1023.0f);
                atomicAdd(&hist[(int)sf], 1);
            }
        } )
    __syncthreads();
    find_crossing(hist, grp, HARD_K_ - chi1, &s_bin2, &s_chi2);
    const float thr = lo1 + s_bin2 * (binw * (1.0f / 1024.0f));

    float sl = 0.0f; int cg = 0;
    FOR_ALL_VALS( if (v > thr) { cg++; sl += __expf((v - m) * INV_T); } )
    #pragma unroll
    for (int o = 32; o > 0; o >>= 1) { sl += __shfl_xor(sl, o); cg += __shfl_xor(cg, o); }
    if ((t & 63) == 0) { scf[t >> 6] = sl; sci[t >> 6] = cg; }
    __syncthreads();
    if (t == 0) {
        const float slt = scf[0] + scf[1] + scf[2] + scf[3];
        const int   cgt = sci[0] + sci[1] + sci[2] + sci[3];
        const float sadj = slt + ((float)HARD_K_ - (float)cgt) * __expf((thr - m) * INV_T);
        lseq[row] = m * INV_T + __logf(sadj);
    }
}

// ---------------------------------------------------------------------------
// Batch lse + positive-pair loss, one WAVE per row (4 rows/block).
// Fixed-reference lse (r6-verified math). NO global atomics: each wave
// stores its (part,cnt) partial to a private slot; finalize reduces.
// ---------------------------------------------------------------------------
__global__ void __launch_bounds__(256) batch_row_loss(const float* __restrict__ S,
                                                      const int* __restrict__ labels,
                                                      const float* __restrict__ lse_queue,
                                                      float* __restrict__ part_out,
                                                      int* __restrict__ cnt_out) {
    const int t = threadIdx.x;
    const int wv = t >> 6, lane = t & 63;
    const int row = blockIdx.x * 4 + wv;
    __shared__ int lab[BATCH_N];
    for (int k = t; k < BATCH_N; k += 256) lab[k] = labels[k];
    __syncthreads();
    const int myLab = lab[row];
    const float4* rp4 = (const float4*)(S + (size_t)row * BATCH_N);
    const int4*   lb4 = (const int4*)lab;

    float v[32]; int lb[32];
    #pragma unroll
    for (int kk = 0; kk < 8; kk++) {
        const float4 f = rp4[lane + 64 * kk];
        const int4   l = lb4[lane + 64 * kk];
        v[4*kk+0] = f.x; v[4*kk+1] = f.y; v[4*kk+2] = f.z; v[4*kk+3] = f.w;
        lb[4*kk+0] = l.x; lb[4*kk+1] = l.y; lb[4*kk+2] = l.z; lb[4*kk+3] = l.w;
    }

    // pass A: negatives exp-sum at fixed reference REF = 1/T
    const float REF = INV_T;
    float sneg = 0.0f;
    #pragma unroll
    for (int k = 0; k < 32; k++) {
        const float ev = __expf(v[k] * INV_T - REF);
        sneg += (lb[k] != myLab) ? ev : 0.0f;
    }
    #pragma unroll
    for (int o = 32; o > 0; o >>= 1) sneg += __shfl_xor(sneg, o);
    const float lseb = (sneg > 0.0f) ? REF + __logf(sneg) : -1e30f;
    const float Lq = lse_queue[row];
    const float mx0 = fmaxf(lseb, Lq), mn0 = fminf(lseb, Lq);
    const float L = mx0 + __logf(1.0f + __expf(mn0 - mx0));

    // pass B: positive-pair terms logaddexp(sv, L) - sv
    float part = 0.0f; int cnt = 0;
    #pragma unroll
    for (int k = 0; k < 32; k++) {
        const int j = (lane + 64 * (k >> 2)) * 4 + (k & 3);
        if (lb[k] == myLab && j != row) {
            const float sv = v[k] * INV_T;
            const float mx = fmaxf(sv, L), mn = fminf(sv, L);
            part += (mx - sv) + __logf(1.0f + __expf(mn - mx));
            cnt++;
        }
    }
    #pragma unroll
    for (int o = 32; o > 0; o >>= 1) { part += __shfl_xor(part, o); cnt += __shfl_xor(cnt, o); }
    if (lane == 0) { part_out[row] = part; cnt_out[row] = cnt; }
}

// reduce 2048 per-row partials -> scalar loss. One block.
__global__ void __launch_bounds__(256) finalize_loss(const float* __restrict__ part,
                                                     const int* __restrict__ cnt,
                                                     float* __restrict__ out) {
    const int t = threadIdx.x;
    float s = 0.0f; int c = 0;
    #pragma unroll
    for (int k = 0; k < 8; k++) { s += part[t + 256 * k]; c += cnt[t + 256 * k]; }
    #pragma unroll
    for (int o = 32; o > 0; o >>= 1) { s += __shfl_xor(s, o); c += __shfl_xor(c, o); }
    __shared__ float sf[4]; __shared__ int sc[4];
    if ((t & 63) == 0) { sf[t >> 6] = s; sc[t >> 6] = c; }
    __syncthreads();
    if (t == 0) {
        const float st = sf[0] + sf[1] + sf[2] + sf[3];
        const int   ct = sc[0] + sc[1] + sc[2] + sc[3];
        out[0] = (ct > 0) ? (st / (float)ct) : 0.0f;
    }
}

// ---------------------------------------------------------------------------
extern "C" void kernel_launch(void* const* d_in, const int* in_sizes, int n_in,
                              void* d_out, int out_size, void* d_ws, size_t ws_size,
                              hipStream_t stream) {
    const float* emb    = (const float*)d_in[0];
    const int*   labels = (const int*)  d_in[1];
    const float* W1     = (const float*)d_in[2];
    const float* b1     = (const float*)d_in[3];
    const float* W2     = (const float*)d_in[4];
    const float* b2     = (const float*)d_in[5];
    const float* queue  = (const float*)d_in[6];
    const int*   qlab   = (const int*)  d_in[7];

    char* ws = (char*)d_ws;
    __half* simsq = (__half*)(ws);                       // [0, 134217728)
    float*  Sbuf  = (float*) (ws);                       // overlays simsq post-topk
    short*  embb  = (short*) (ws + 134217728);           // 3145728
    short*  hbf   = (short*) (ws + 137363456);           // 3145728
    float*  z     = (float*) (ws + 140509184);           // 1048576
    short*  zb    = (short*) (ws + 141557760);           // 524288
    short*  qb    = (short*) (ws + 142082048);           // 8388608
    short*  w1t   = (short*) (ws + 150470656);           // 1179648
    short*  w2t   = (short*) (ws + 151650304);           // 196608
    float*  lseq  = (float*) (ws + 151846912);           // 8192
    int*    flag  = (int*)   (ws + 151855104);           // 8192
    int*    qcnt  = (int*)   (ws + 151863296);           // 64
    float*  partb = (float*) (ws + 151863360);           // 8192
    int*    cntb  = (int*)   (ws + 151871552);           // 8192

    hipMemsetAsync(ws + 151855104, 0, 8192 + 64, stream);   // flag + qcnt only

    dim3 blk(256);
    cast_bf16_vec<<<dim3(BATCH_N * EMB_D_ / 4 / 256), blk, 0, stream>>>(emb, embb, BATCH_N * EMB_D_ / 4);
    cast_bf16_vec<<<dim3(QUEUE_N * PROJ_D_ / 4 / 256), blk, 0, stream>>>(queue, qb, QUEUE_N * PROJ_D_ / 4);
    transpose_cast<<<dim3(EMB_D_ / 64, EMB_D_ / 64), blk, 0, stream>>>(W1, w1t, EMB_D_, EMB_D_);
    transpose_cast<<<dim3(PROJ_D_ / 64, EMB_D_ / 64), blk, 0, stream>>>(W2, w2t, EMB_D_, PROJ_D_);
    count_qlab<<<dim3(32), blk, 0, stream>>>(qlab, qcnt);
    mfma_nt_k<short, true ><<<dim3(EMB_D_ / 128, BATCH_N / 128), blk, 0, stream>>>(embb, w1t, b1, hbf, EMB_D_, EMB_D_);
    mfma_nt_k<float, false><<<dim3(PROJ_D_ / 128, BATCH_N / 128), blk, 0, stream>>>(hbf, w2t, b2, z, PROJ_D_, EMB_D_);
    normalize_cast<<<BATCH_N, PROJ_D_, 0, stream>>>(z, zb);
    mfma_nt<__half, true><<<dim3(QUEUE_N / 128, BATCH_N / 128), blk, 0, stream>>>(
        zb, qb, simsq, QUEUE_N, labels, qlab);
    topk_lse_stream<<<BATCH_N, 256, 0, stream>>>(simsq, qcnt, labels, lseq, flag);
    topk_lse_fallback<<<BATCH_N, 256, 0, stream>>>(zb, qb, labels, qlab, qcnt, flag, lseq);
    mfma_nt<float, false><<<dim3(BATCH_N / 128, BATCH_N / 128), blk, 0, stream>>>(
        zb, zb, Sbuf, BATCH_N, nullptr, nullptr);
    batch_row_loss<<<BATCH_N / 4, 256, 0, stream>>>(Sbuf, labels, lseq, partb, cntb);
    finalize_loss<<<1, 256, 0, stream>>>(partb, cntb, (float*)d_out);
}